// Round 2
// baseline (453.102 us; speedup 1.0000x reference)
//
#include <hip/hip_runtime.h>

#define B_   64
#define P_   12273
#define J_   80
#define MOT_ 94
#define K_   64
#define H_   128
#define Q_   340      // NB*WN
#define NE_  36819    // P*3
#define MK_  6016     // MOT*K
#define PW_  12288    // padded P for w_t rows
#define STG_ 2356416  // B_*NE_ floats per staging buffer

typedef float v4f  __attribute__((ext_vector_type(4)));
typedef float v8f  __attribute__((ext_vector_type(8)));
typedef float v16f __attribute__((ext_vector_type(16)));
#define AS4 __attribute__((address_space(4)))

__device__ __forceinline__ const AS4 float* unif(const float* p){
  return (const AS4 float*)(unsigned long long)p;
}
__device__ __forceinline__ const AS4 v4f* univ4(const float* p){
  return (const AS4 v4f*)(unsigned long long)p;
}
__device__ __forceinline__ const AS4 v16f* univ16(const float* p){
  return (const AS4 v16f*)(unsigned long long)p;
}

// ---- K1 "prep": fieldnet + tm transpose + skin transpose + dk_t=bd + lacc=0
__global__ __launch_bounds__(256) void k_prep(
    const float* __restrict__ query, const float* __restrict__ mwl,
    const float* __restrict__ tm,    const float* __restrict__ W1,
    const float* __restrict__ b1,    const float* __restrict__ W2,
    const float* __restrict__ b2,    const float* __restrict__ cps,
    const float* __restrict__ cpm,   const float* __restrict__ cts,
    const float* __restrict__ ctm,   const float* __restrict__ skin,
    const float* __restrict__ bd,
    float* __restrict__ G,           float* __restrict__ tm_t,
    float* __restrict__ w_t,         float* __restrict__ dk_t,
    float* __restrict__ lacc)
{
  __shared__ float smem[80 * 65];
  int blk = blockIdx.x;
  int t = threadIdx.x;
  if (blk < 1280){
    int lane = t & 63;
    int wid = __builtin_amdgcn_readfirstlane(t >> 6);
    int bj = blk * 4 + wid;
    int b = bj / J_, l = bj - b * J_;
    float* hs = smem + wid * 80;
    float acc = 0.f;
    const AS4 float* mp = unif(mwl + l * MOT_);
    const float* tp = tm + (size_t)b * MK_ + lane;
    float tbuf[4];
    #pragma unroll
    for (int s = 0; s < 4; s++) tbuf[s] = tp[s * K_];
    #pragma unroll 4
    for (int j = 0; j < MOT_; j++){
      float tv = tbuf[j & 3];
      if (j + 4 < MOT_) tbuf[j & 3] = tp[(j + 4) * K_];
      float w = mp[j]; w = w > 0.f ? w : 0.f;
      acc = fmaf(w, tv, acc);
    }
    hs[3 + lane] = acc;
    if (lane < 3) hs[lane] = query[(size_t)bj * 3 + lane];
    __syncthreads();
    float a1 = b1[lane], a2 = b1[lane + 64];
    float wa[4], wb[4];
    #pragma unroll
    for (int s = 0; s < 4; s++){
      wa[s] = W1[s * H_ + lane];
      wb[s] = W1[s * H_ + 64 + lane];
    }
    #pragma unroll 4
    for (int i = 0; i < 67; i++){
      float hv = hs[i];
      float va = wa[i & 3], vb = wb[i & 3];
      if (i + 4 < 67){
        wa[i & 3] = W1[(i + 4) * H_ + lane];
        wb[i & 3] = W1[(i + 4) * H_ + 64 + lane];
      }
      a1 = fmaf(hv, va, a1);
      a2 = fmaf(hv, vb, a2);
    }
    a1 = a1 > 0.f ? a1 : 0.f;
    a2 = a2 > 0.f ? a2 : 0.f;
    const AS4 float* b2c = unif(b2);
    float rt[6];
    #pragma unroll
    for (int o = 0; o < 6; o++){
      float po = fmaf(a1, W2[lane * 6 + o], a2 * W2[(lane + 64) * 6 + o]);
      #pragma unroll
      for (int off = 32; off; off >>= 1) po += __shfl_xor(po, off);
      rt[o] = po + b2c[o];
    }
    const float D2R = 0.017453292519943295f;
    float ax = fmaf(rt[0], cps[0], cpm[0]) * D2R;
    float ay = fmaf(rt[1], cps[1], cpm[1]) * D2R;
    float az = fmaf(rt[2], cps[2], cpm[2]) * D2R;
    float tx = fmaf(hs[0] + rt[3], cts[0], ctm[0]);
    float ty = fmaf(hs[1] + rt[4], cts[1], ctm[1]);
    float tz = fmaf(hs[2] + rt[5], cts[2], ctm[2]);
    float sx, cx, sy, cy, sz, cz;
    sincosf(ax, &sx, &cx); sincosf(ay, &sy, &cy); sincosf(az, &sz, &cz);
    if (lane == 0){
      float4 r0 = make_float4(cz*cy, cz*sy*sx - sz*cx, cz*sy*cx + sz*sx, tx);
      float4 r1 = make_float4(sz*cy, sz*sy*sx + cz*cx, sz*sy*cx - cz*sx, ty);
      float4 r2 = make_float4(-sy,   cy*sx,            cy*cx,            tz);
      float4* g = (float4*)(G + (size_t)bj * 12);
      g[0] = r0; g[1] = r1; g[2] = r2;
    }
  } else if (blk < 1374){
    int m0 = (blk - 1280) * 64;
    int ml = t & 63, g = t >> 6;
    #pragma unroll
    for (int r = 0; r < 16; r++){
      int b = g * 16 + r;
      smem[ml * 65 + b] = tm[(size_t)b * MK_ + m0 + ml];
    }
    __syncthreads();
    int bl = t & 63;
    #pragma unroll
    for (int r = 0; r < 16; r++){
      int m = g * 16 + r;
      tm_t[(size_t)(m0 + m) * 64 + bl] = smem[m * 65 + bl];
    }
  } else if (blk < 1566){
    int p0 = (blk - 1374) * 64;
    #pragma unroll
    for (int k = 0; k < 20; k++){
      int idx = k * 256 + t;
      int pl = idx / 80, j = idx - pl * 80;
      int p = p0 + pl;
      smem[j * 65 + pl] = (p < P_) ? skin[(size_t)p * J_ + j] : 0.f;
    }
    __syncthreads();
    #pragma unroll
    for (int k = 0; k < 20; k++){
      int idx = k * 256 + t;
      int j = idx >> 6, pl = idx & 63;
      w_t[(size_t)j * PW_ + p0 + pl] = smem[j * 65 + pl];
    }
  } else if (blk < 1651){
    int idx = (blk - 1566) * 256 + t;        // 85*256 = 21760 = Q_*B_
    dk_t[idx] = bd[idx >> 6];
  } else {
    if (t < 2) lacc[t] = 0.f;
  }
}

// ---- K2: detailkey GEMM, atomic accumulation into dk_t (init'd to bd by k_prep).
//      grid (6, 94). Wave wid owns b-slice [wid*16,+16). Wd prefetch 8-deep,
//      tm_t s_load rows 4-deep circular. No part buffer, no reduce kernel.
__global__ __launch_bounds__(256) void k_dkey(
    const float* __restrict__ tm_t, const float* __restrict__ Wd,
    float* __restrict__ dk_t)
{
  int t = threadIdx.x;
  int lane = t & 63;
  int wid = __builtin_amdgcn_readfirstlane(t >> 6);
  int qt = blockIdx.x;
  int q = qt * 64 + lane;
  bool vq = q < Q_;
  int m0 = blockIdx.y * 64;
  const AS4 v16f* tr = univ16(tm_t);
  float acc[16];
  #pragma unroll
  for (int i = 0; i < 16; i++) acc[i] = 0.f;
  float wbuf[8];
  #pragma unroll
  for (int s = 0; s < 8; s++)
    wbuf[s] = vq ? Wd[(size_t)(m0 + s) * Q_ + q] : 0.f;
  v16f tb[4];
  #pragma unroll
  for (int s = 0; s < 4; s++) tb[s] = tr[(size_t)(m0 + s) * 4 + wid];
  #pragma unroll 8
  for (int mm = 0; mm < 64; mm++){
    float wd = wbuf[mm & 7];
    if (mm + 8 < 64) wbuf[mm & 7] = vq ? Wd[(size_t)(m0 + mm + 8) * Q_ + q] : 0.f;
    v16f tv = tb[mm & 3];
    if (mm + 4 < 64) tb[mm & 3] = tr[(size_t)(m0 + mm + 4) * 4 + wid];
    #pragma unroll
    for (int i = 0; i < 16; i++) acc[i] = fmaf(tv[i], wd, acc[i]);
  }
  if (vq){
    float* dp = dk_t + (size_t)q * 64 + wid * 16;
    #pragma unroll
    for (int i = 0; i < 16; i++) atomicAdd(&dp[i], acc[i]);
  }
}

// ---- K4: detail einsum. Depth-4 (20-row) DPSD circular prefetch with static
//      slot indices (no register copies -> vmcnt waits land at consume).
//      dk rows stay wave-uniform SGPRs (s_load_dwordx16 x5 per group).
//      q split into up to 4 chunks for occupancy; chunks 0..n-2 -> stg[y],
//      last chunk -> out (raw acc; scale fused in k_skin).
__device__ __forceinline__ void dk_consume(const AS4 v16f* dkv, int qa, int wid,
                                           const float* dc, float* acc,
                                           float& sq, bool doSq)
{
  v16f r0 = dkv[(qa + 0) * 4 + wid];
  v16f r1 = dkv[(qa + 1) * 4 + wid];
  v16f r2 = dkv[(qa + 2) * 4 + wid];
  v16f r3 = dkv[(qa + 3) * 4 + wid];
  v16f r4 = dkv[(qa + 4) * 4 + wid];
  if (doSq){
    #pragma unroll
    for (int i = 0; i < 5; i++) sq = fmaf(dc[i], dc[i], sq);
  }
  #pragma unroll
  for (int i = 0; i < 16; i++){
    acc[i] = fmaf(r0[i], dc[0], acc[i]);
    acc[i] = fmaf(r1[i], dc[1], acc[i]);
    acc[i] = fmaf(r2[i], dc[2], acc[i]);
    acc[i] = fmaf(r3[i], dc[3], acc[i]);
    acc[i] = fmaf(r4[i], dc[4], acc[i]);
  }
}

__global__ __launch_bounds__(256) void k_detail(
    const float* __restrict__ DPSD, const float* __restrict__ dk_t,
    float* __restrict__ stg, float* __restrict__ out,
    float* __restrict__ lacc, int qn)
{
  int t = threadIdx.x;
  int lane = t & 63;
  int wid = __builtin_amdgcn_readfirstlane(t >> 6);  // 0..3
  int b0 = wid * 16;
  int e = blockIdx.x * 64 + lane;
  bool ve = e < NE_;
  int q0 = blockIdx.y * qn;
  const AS4 v16f* dkv = univ16(dk_t);
  const float* Dp = DPSD + (ve ? e : 0);
  float acc[16];
  #pragma unroll
  for (int i = 0; i < 16; i++) acc[i] = 0.f;
  float sq = 0.f;
  bool doSq = (wid == 0);
  int ng = qn / 5;                  // 68 / 34 / 17
  float buf[4][5];
  #pragma unroll
  for (int s = 0; s < 4; s++){
    #pragma unroll
    for (int i = 0; i < 5; i++)
      buf[s][i] = Dp[(size_t)(q0 + s * 5 + i) * NE_];
  }
  for (int g = 0; g < ng; g += 4){
    #pragma unroll
    for (int s = 0; s < 4; s++){
      int gg = g + s;
      if (gg < ng){
        dk_consume(dkv, q0 + gg * 5, wid, buf[s], acc, sq, doSq);
        int gp = gg + 4;
        if (gp < ng){
          #pragma unroll
          for (int i = 0; i < 5; i++)
            buf[s][i] = Dp[(size_t)(q0 + gp * 5 + i) * NE_];
        }
      }
    }
  }
  if (ve){
    bool toOut = (blockIdx.y + 1 == gridDim.y);
    float* dst = toOut ? (out + 1 + e) : (stg + (size_t)blockIdx.y * STG_ + e);
    #pragma unroll
    for (int i = 0; i < 16; i++)
      dst[(size_t)(b0 + i) * NE_] = acc[i];
  }
  if (doSq){
    if (!ve) sq = 0.f;
    #pragma unroll
    for (int off = 32; off; off >>= 1) sq += __shfl_xor(sq, off);
    if (lane == 0) atomicAdd(&lacc[1], sq);
  }
}

// ---- K5: LBS skinning. G block-slice (8 b = 30KB) staged in LDS once;
//      j-loop reads it as uniform broadcast ds_read_b128 (latency hidden in
//      unroll-8 window); w_t prefetched 8-deep circular. Combines detail
//      chunks + scale + loss.
__global__ __launch_bounds__(256) void k_skin(
    const float* __restrict__ G, const float* __restrict__ w_t,
    const float* __restrict__ rest, const float* __restrict__ in_pc,
    const float* __restrict__ stg, const float* __restrict__ rstd,
    const float* __restrict__ rmean,
    float* __restrict__ out, float* __restrict__ lacc, int nst)
{
  __shared__ float gs[7680];        // 8 b * 80 j * 12
  __shared__ float red[4];
  int t = threadIdx.x;
  int lane = t & 63;
  int wid = __builtin_amdgcn_readfirstlane(t >> 6);  // 0..3
  {
    const float4* Gv = (const float4*)(G + (size_t)blockIdx.y * 7680);
    float4* gv = (float4*)gs;
    #pragma unroll
    for (int it = 0; it < 8; it++){
      int idx = it * 256 + t;
      if (idx < 1920) gv[idx] = Gv[idx];
    }
  }
  __syncthreads();
  int p  = blockIdx.x * 64 + lane;
  int bA = blockIdx.y * 8 + wid * 2;
  const float4* gsA = (const float4*)(gs + (wid * 2) * 960);
  const float4* gsB = gsA + 240;
  float accA[12], accB[12];
  #pragma unroll
  for (int c = 0; c < 12; c++){ accA[c] = 0.f; accB[c] = 0.f; }
  const float* wp = w_t + p;
  float wbuf[8];
  #pragma unroll
  for (int s = 0; s < 8; s++) wbuf[s] = wp[(size_t)s * PW_];
  #pragma unroll 8
  for (int j = 0; j < J_; j++){
    float w = wbuf[j & 7];
    if (j + 8 < J_) wbuf[j & 7] = wp[(size_t)(j + 8) * PW_];
    float4 a0 = gsA[j * 3], a1 = gsA[j * 3 + 1], a2 = gsA[j * 3 + 2];
    float4 c0 = gsB[j * 3], c1 = gsB[j * 3 + 1], c2 = gsB[j * 3 + 2];
    accA[0]  = fmaf(w, a0.x, accA[0]);  accA[1]  = fmaf(w, a0.y, accA[1]);
    accA[2]  = fmaf(w, a0.z, accA[2]);  accA[3]  = fmaf(w, a0.w, accA[3]);
    accA[4]  = fmaf(w, a1.x, accA[4]);  accA[5]  = fmaf(w, a1.y, accA[5]);
    accA[6]  = fmaf(w, a1.z, accA[6]);  accA[7]  = fmaf(w, a1.w, accA[7]);
    accA[8]  = fmaf(w, a2.x, accA[8]);  accA[9]  = fmaf(w, a2.y, accA[9]);
    accA[10] = fmaf(w, a2.z, accA[10]); accA[11] = fmaf(w, a2.w, accA[11]);
    accB[0]  = fmaf(w, c0.x, accB[0]);  accB[1]  = fmaf(w, c0.y, accB[1]);
    accB[2]  = fmaf(w, c0.z, accB[2]);  accB[3]  = fmaf(w, c0.w, accB[3]);
    accB[4]  = fmaf(w, c1.x, accB[4]);  accB[5]  = fmaf(w, c1.y, accB[5]);
    accB[6]  = fmaf(w, c1.z, accB[6]);  accB[7]  = fmaf(w, c1.w, accB[7]);
    accB[8]  = fmaf(w, c2.x, accB[8]);  accB[9]  = fmaf(w, c2.y, accB[9]);
    accB[10] = fmaf(w, c2.z, accB[10]); accB[11] = fmaf(w, c2.w, accB[11]);
  }
  bool vp = p < P_;
  float vx = 0.f, vy = 0.f, vz = 0.f;
  if (vp){ vx = rest[p * 3]; vy = rest[p * 3 + 1]; vz = rest[p * 3 + 2]; }
  float srs[3], srm[3];
  #pragma unroll
  for (int x = 0; x < 3; x++){ srs[x] = rstd[x]; srm[x] = rmean[x]; }
  float lsum = 0.f;
  if (vp){
    size_t baseA = ((size_t)bA * P_ + p) * 3;
    size_t baseB = baseA + (size_t)P_ * 3;
    #pragma unroll
    for (int x = 0; x < 3; x++){
      float det = out[1 + baseA + x];
      for (int s = 0; s < nst; s++) det += stg[(size_t)s * STG_ + baseA + x];
      float v = fmaf(accA[x*4+0], vx, fmaf(accA[x*4+1], vy, fmaf(accA[x*4+2], vz, accA[x*4+3])));
      v += fmaf(det, srs[x], srm[x]);
      lsum += fabsf(in_pc[baseA + x] - v);
      out[1 + baseA + x] = v;
    }
    #pragma unroll
    for (int x = 0; x < 3; x++){
      float det = out[1 + baseB + x];
      for (int s = 0; s < nst; s++) det += stg[(size_t)s * STG_ + baseB + x];
      float v = fmaf(accB[x*4+0], vx, fmaf(accB[x*4+1], vy, fmaf(accB[x*4+2], vz, accB[x*4+3])));
      v += fmaf(det, srs[x], srm[x]);
      lsum += fabsf(in_pc[baseB + x] - v);
      out[1 + baseB + x] = v;
    }
  }
  #pragma unroll
  for (int off = 32; off; off >>= 1) lsum += __shfl_xor(lsum, off);
  if (lane == 0) red[wid] = lsum;
  __syncthreads();
  if (t == 0) atomicAdd(&lacc[0], red[0] + red[1] + red[2] + red[3]);
}

// ---- K6: finalize scalar loss
__global__ void k_finalize(const float* __restrict__ lacc, float* __restrict__ out){
  if (threadIdx.x == 0 && blockIdx.x == 0){
    float loss = lacc[0] * (1.f / 2356416.f) + 1e-4f * (lacc[1] * (1.f / 12518460.f));
    out[0] = loss;
  }
}

extern "C" void kernel_launch(void* const* d_in, const int* in_sizes, int n_in,
                              void* d_out, int out_size, void* d_ws, size_t ws_size,
                              hipStream_t stream){
  const float* in_pc = (const float*)d_in[0];
  const float* rest  = (const float*)d_in[2];
  const float* skin  = (const float*)d_in[3];
  const float* mwl   = (const float*)d_in[4];
  const float* query = (const float*)d_in[5];
  const float* cps   = (const float*)d_in[6];
  const float* cpm   = (const float*)d_in[7];
  const float* cts   = (const float*)d_in[8];
  const float* ctm   = (const float*)d_in[9];
  const float* W1    = (const float*)d_in[10];
  const float* b1    = (const float*)d_in[11];
  const float* W2    = (const float*)d_in[12];
  const float* b2    = (const float*)d_in[13];
  const float* tm    = (const float*)d_in[14];
  const float* Wd    = (const float*)d_in[15];
  const float* bd    = (const float*)d_in[16];
  const float* DPSD  = (const float*)d_in[17];
  const float* rstd  = (const float*)d_in[18];
  const float* rmean = (const float*)d_in[19];
  float* out = (float*)d_out;

  float* ws   = (float*)d_ws;
  float* G    = ws;                 // 61440
  float* dk_t = G + 61440;          // 21760
  float* lacc = dk_t + 21760;       // 64 (pad)
  float* tm_t = lacc + 64;          // 385024
  float* w_t  = tm_t + 385024;      // 983040
  float* stg  = w_t + 983040;       // up to 3 * STG_ staging buffers

  size_t have = ws_size / 4;
  const size_t base = 1451328;
  int nqh = 1;
  if (have >= base + 3 * (size_t)STG_)      nqh = 4;
  else if (have >= base + (size_t)STG_)     nqh = 2;
  int qn = Q_ / nqh;                // 340 / 170 / 85, all multiples of 5

  k_prep    <<<1652, 256, 0, stream>>>(query, mwl, tm, W1, b1, W2, b2,
                                       cps, cpm, cts, ctm, skin, bd,
                                       G, tm_t, w_t, dk_t, lacc);
  k_dkey    <<<dim3(6, 94), 256, 0, stream>>>(tm_t, Wd, dk_t);
  k_detail  <<<dim3(576, nqh), 256, 0, stream>>>(DPSD, dk_t, stg, out, lacc, qn);
  k_skin    <<<dim3(192, 8), 256, 0, stream>>>(G, w_t, rest, in_pc, stg, rstd, rmean,
                                               out, lacc, nqh - 1);
  k_finalize<<<1, 64, 0, stream>>>(lacc, out);
}

// Round 3
// 310.339 us; speedup vs baseline: 1.4600x; 1.4600x over previous
//
#include <hip/hip_runtime.h>

#define B_   64
#define P_   12273
#define J_   80
#define MOT_ 94
#define K_   64
#define H_   128
#define Q_   340      // NB*WN
#define NE_  36819    // P*3
#define MK_  6016     // MOT*K
#define PW_  12288    // padded P for w_t rows
#define STG_ 2356416  // B_*NE_ floats per staging buffer

typedef float v4f  __attribute__((ext_vector_type(4)));
typedef float v8f  __attribute__((ext_vector_type(8)));
typedef float v16f __attribute__((ext_vector_type(16)));
#define AS4 __attribute__((address_space(4)))

__device__ __forceinline__ const AS4 float* unif(const float* p){
  return (const AS4 float*)(unsigned long long)p;
}
__device__ __forceinline__ const AS4 v4f* univ4(const float* p){
  return (const AS4 v4f*)(unsigned long long)p;
}
__device__ __forceinline__ const AS4 v16f* univ16(const float* p){
  return (const AS4 v16f*)(unsigned long long)p;
}

// ---- K1 "prep": fieldnet + tm transpose + skin transpose + lacc init
__global__ __launch_bounds__(256) void k_prep(
    const float* __restrict__ query, const float* __restrict__ mwl,
    const float* __restrict__ tm,    const float* __restrict__ W1,
    const float* __restrict__ b1,    const float* __restrict__ W2,
    const float* __restrict__ b2,    const float* __restrict__ cps,
    const float* __restrict__ cpm,   const float* __restrict__ cts,
    const float* __restrict__ ctm,   const float* __restrict__ skin,
    float* __restrict__ G,           float* __restrict__ tm_t,
    float* __restrict__ w_t,         float* __restrict__ lacc)
{
  __shared__ float smem[80 * 65];
  int blk = blockIdx.x;
  int t = threadIdx.x;
  if (blk < 1280){
    int lane = t & 63;
    int wid = __builtin_amdgcn_readfirstlane(t >> 6);
    int bj = blk * 4 + wid;
    int b = bj / J_, l = bj - b * J_;
    float* hs = smem + wid * 80;
    float acc = 0.f;
    const AS4 float* mp = unif(mwl + l * MOT_);
    const float* tp = tm + (size_t)b * MK_ + lane;
    float tbuf[4];
    #pragma unroll
    for (int s = 0; s < 4; s++) tbuf[s] = tp[s * K_];
    #pragma unroll 4
    for (int j = 0; j < MOT_; j++){
      float tv = tbuf[j & 3];
      if (j + 4 < MOT_) tbuf[j & 3] = tp[(j + 4) * K_];
      float w = mp[j]; w = w > 0.f ? w : 0.f;
      acc = fmaf(w, tv, acc);
    }
    hs[3 + lane] = acc;
    if (lane < 3) hs[lane] = query[(size_t)bj * 3 + lane];
    __syncthreads();
    float a1 = b1[lane], a2 = b1[lane + 64];
    float wa[4], wb[4];
    #pragma unroll
    for (int s = 0; s < 4; s++){
      wa[s] = W1[s * H_ + lane];
      wb[s] = W1[s * H_ + 64 + lane];
    }
    #pragma unroll 4
    for (int i = 0; i < 67; i++){
      float hv = hs[i];
      float va = wa[i & 3], vb = wb[i & 3];
      if (i + 4 < 67){
        wa[i & 3] = W1[(i + 4) * H_ + lane];
        wb[i & 3] = W1[(i + 4) * H_ + 64 + lane];
      }
      a1 = fmaf(hv, va, a1);
      a2 = fmaf(hv, vb, a2);
    }
    a1 = a1 > 0.f ? a1 : 0.f;
    a2 = a2 > 0.f ? a2 : 0.f;
    const AS4 float* b2c = unif(b2);
    float rt[6];
    #pragma unroll
    for (int o = 0; o < 6; o++){
      float po = fmaf(a1, W2[lane * 6 + o], a2 * W2[(lane + 64) * 6 + o]);
      #pragma unroll
      for (int off = 32; off; off >>= 1) po += __shfl_xor(po, off);
      rt[o] = po + b2c[o];
    }
    const float D2R = 0.017453292519943295f;
    float ax = fmaf(rt[0], cps[0], cpm[0]) * D2R;
    float ay = fmaf(rt[1], cps[1], cpm[1]) * D2R;
    float az = fmaf(rt[2], cps[2], cpm[2]) * D2R;
    float tx = fmaf(hs[0] + rt[3], cts[0], ctm[0]);
    float ty = fmaf(hs[1] + rt[4], cts[1], ctm[1]);
    float tz = fmaf(hs[2] + rt[5], cts[2], ctm[2]);
    float sx, cx, sy, cy, sz, cz;
    sincosf(ax, &sx, &cx); sincosf(ay, &sy, &cy); sincosf(az, &sz, &cz);
    if (lane == 0){
      float4 r0 = make_float4(cz*cy, cz*sy*sx - sz*cx, cz*sy*cx + sz*sx, tx);
      float4 r1 = make_float4(sz*cy, sz*sy*sx + cz*cx, sz*sy*cx - cz*sx, ty);
      float4 r2 = make_float4(-sy,   cy*sx,            cy*cx,            tz);
      float4* g = (float4*)(G + (size_t)bj * 12);
      g[0] = r0; g[1] = r1; g[2] = r2;
    }
  } else if (blk < 1374){
    int m0 = (blk - 1280) * 64;
    int ml = t & 63, g = t >> 6;
    #pragma unroll
    for (int r = 0; r < 16; r++){
      int b = g * 16 + r;
      smem[ml * 65 + b] = tm[(size_t)b * MK_ + m0 + ml];
    }
    __syncthreads();
    int bl = t & 63;
    #pragma unroll
    for (int r = 0; r < 16; r++){
      int m = g * 16 + r;
      tm_t[(size_t)(m0 + m) * 64 + bl] = smem[m * 65 + bl];
    }
  } else if (blk < 1566){
    int p0 = (blk - 1374) * 64;
    #pragma unroll
    for (int k = 0; k < 20; k++){
      int idx = k * 256 + t;
      int pl = idx / 80, j = idx - pl * 80;
      int p = p0 + pl;
      smem[j * 65 + pl] = (p < P_) ? skin[(size_t)p * J_ + j] : 0.f;
    }
    __syncthreads();
    #pragma unroll
    for (int k = 0; k < 20; k++){
      int idx = k * 256 + t;
      int j = idx >> 6, pl = idx & 63;
      w_t[(size_t)j * PW_ + p0 + pl] = smem[j * 65 + pl];
    }
  } else {
    if (t < 2) lacc[t] = 0.f;
  }
}

// ---- K2: detailkey partial GEMM. grid (6, 94). Private part slices, no atomics.
__global__ __launch_bounds__(256) void k_dkey(
    const float* __restrict__ tm_t, const float* __restrict__ Wd,
    float* __restrict__ part)
{
  int t = threadIdx.x;
  int lane = t & 63;
  int wid = __builtin_amdgcn_readfirstlane(t >> 6);
  int qt = blockIdx.x;
  int q = qt * 64 + lane;
  bool vq = q < Q_;
  int m0 = blockIdx.y * 64;
  const AS4 v16f* tr = univ16(tm_t);
  float acc[16];
  #pragma unroll
  for (int i = 0; i < 16; i++) acc[i] = 0.f;
  float wbuf[4];
  #pragma unroll
  for (int i = 0; i < 4; i++)
    wbuf[i] = vq ? Wd[(size_t)(m0 + i) * Q_ + q] : 0.f;
  v16f tb0 = tr[(size_t)(m0 + 0) * 4 + wid];
  v16f tb1 = tr[(size_t)(m0 + 1) * 4 + wid];
  #pragma unroll 4
  for (int mm = 0; mm < 60; mm++){
    float wd = wbuf[mm & 3];
    wbuf[mm & 3] = vq ? Wd[(size_t)(m0 + mm + 4) * Q_ + q] : 0.f;
    v16f tv = tb0; tb0 = tb1;
    tb1 = tr[(size_t)(m0 + mm + 2) * 4 + wid];
    #pragma unroll
    for (int i = 0; i < 16; i++) acc[i] = fmaf(tv[i], wd, acc[i]);
  }
  #pragma unroll
  for (int mm = 60; mm < 64; mm++){
    float wd = wbuf[mm & 3];
    v16f tv = tb0; tb0 = tb1;
    if (mm < 62) tb1 = tr[(size_t)(m0 + mm + 2) * 4 + wid];
    #pragma unroll
    for (int i = 0; i < 16; i++) acc[i] = fmaf(tv[i], wd, acc[i]);
  }
  float* pb = part + ((size_t)blockIdx.y * 6 + qt) * 4096 + (size_t)(wid * 16) * 64;
  #pragma unroll
  for (int i = 0; i < 16; i++) pb[i * 64 + lane] = acc[i];
}

// ---- K3: reduce partials + bd -> dk_t[q*64+b]. 680 blocks, 8-way d-split per j.
__global__ __launch_bounds__(256) void k_dkred(
    const float* __restrict__ part, const float* __restrict__ bd,
    float* __restrict__ dk_t, int S)
{
  int t = threadIdx.x;
  int jj = blockIdx.x * 32 + (t >> 3);   // 680*32 = 21760 = B_*Q_ exactly
  int dl = t & 7;
  int b = jj / Q_, q = jj - b * Q_;
  int qt = q >> 6, ql = q & 63;
  const float* pp = part + (size_t)qt * 4096 + b * 64 + ql;
  float s = 0.f;
  for (int d = dl; d < S; d += 8) s += pp[(size_t)d * 6 * 4096];
  s += __shfl_xor(s, 1); s += __shfl_xor(s, 2); s += __shfl_xor(s, 4);
  if (dl == 0) dk_t[q * 64 + b] = bd[q] + s;
}

// ---- K4: detail einsum. Depth-4 (20-row) DPSD circular prefetch with static
//      slot indices; dk rows wave-uniform via s_load. q split for occupancy.
__device__ __forceinline__ void dk_consume(const AS4 v16f* dkv, int qa, int wid,
                                           const float* dc, float* acc,
                                           float& sq, bool doSq)
{
  v16f r0 = dkv[(qa + 0) * 4 + wid];
  v16f r1 = dkv[(qa + 1) * 4 + wid];
  v16f r2 = dkv[(qa + 2) * 4 + wid];
  v16f r3 = dkv[(qa + 3) * 4 + wid];
  v16f r4 = dkv[(qa + 4) * 4 + wid];
  if (doSq){
    #pragma unroll
    for (int i = 0; i < 5; i++) sq = fmaf(dc[i], dc[i], sq);
  }
  #pragma unroll
  for (int i = 0; i < 16; i++){
    acc[i] = fmaf(r0[i], dc[0], acc[i]);
    acc[i] = fmaf(r1[i], dc[1], acc[i]);
    acc[i] = fmaf(r2[i], dc[2], acc[i]);
    acc[i] = fmaf(r3[i], dc[3], acc[i]);
    acc[i] = fmaf(r4[i], dc[4], acc[i]);
  }
}

__global__ __launch_bounds__(256) void k_detail(
    const float* __restrict__ DPSD, const float* __restrict__ dk_t,
    float* __restrict__ stg, float* __restrict__ out,
    float* __restrict__ lacc, int qn)
{
  int t = threadIdx.x;
  int lane = t & 63;
  int wid = __builtin_amdgcn_readfirstlane(t >> 6);  // 0..3
  int b0 = wid * 16;
  int e = blockIdx.x * 64 + lane;
  bool ve = e < NE_;
  int q0 = blockIdx.y * qn;
  const AS4 v16f* dkv = univ16(dk_t);
  const float* Dp = DPSD + (ve ? e : 0);
  float acc[16];
  #pragma unroll
  for (int i = 0; i < 16; i++) acc[i] = 0.f;
  float sq = 0.f;
  bool doSq = (wid == 0);
  int ng = qn / 5;                  // 68 / 34
  float buf[4][5];
  #pragma unroll
  for (int s = 0; s < 4; s++){
    #pragma unroll
    for (int i = 0; i < 5; i++)
      buf[s][i] = Dp[(size_t)(q0 + s * 5 + i) * NE_];
  }
  for (int g = 0; g < ng; g += 4){
    #pragma unroll
    for (int s = 0; s < 4; s++){
      int gg = g + s;
      if (gg < ng){
        dk_consume(dkv, q0 + gg * 5, wid, buf[s], acc, sq, doSq);
        int gp = gg + 4;
        if (gp < ng){
          #pragma unroll
          for (int i = 0; i < 5; i++)
            buf[s][i] = Dp[(size_t)(q0 + gp * 5 + i) * NE_];
        }
      }
    }
  }
  if (ve){
    bool toOut = (blockIdx.y + 1 == gridDim.y);
    float* dst = toOut ? (out + 1 + e) : (stg + (size_t)blockIdx.y * STG_ + e);
    #pragma unroll
    for (int i = 0; i < 16; i++)
      dst[(size_t)(b0 + i) * NE_] = acc[i];
  }
  if (doSq){
    if (!ve) sq = 0.f;
    #pragma unroll
    for (int off = 32; off; off >>= 1) sq += __shfl_xor(sq, off);
    if (lane == 0) atomicAdd(&lacc[1], sq);
  }
}

// ---- K5: LBS skinning. G block-slice (8 b = 30KB) staged in LDS once;
//      j-loop reads uniform broadcast; w_t prefetched 8-deep circular.
__global__ __launch_bounds__(256) void k_skin(
    const float* __restrict__ G, const float* __restrict__ w_t,
    const float* __restrict__ rest, const float* __restrict__ in_pc,
    const float* __restrict__ stg, const float* __restrict__ rstd,
    const float* __restrict__ rmean,
    float* __restrict__ out, float* __restrict__ lacc, int nst)
{
  __shared__ float gs[7680];        // 8 b * 80 j * 12
  __shared__ float red[4];
  int t = threadIdx.x;
  int lane = t & 63;
  int wid = __builtin_amdgcn_readfirstlane(t >> 6);  // 0..3
  {
    const float4* Gv = (const float4*)(G + (size_t)blockIdx.y * 7680);
    float4* gv = (float4*)gs;
    #pragma unroll
    for (int it = 0; it < 8; it++){
      int idx = it * 256 + t;
      if (idx < 1920) gv[idx] = Gv[idx];
    }
  }
  __syncthreads();
  int p  = blockIdx.x * 64 + lane;
  int bA = blockIdx.y * 8 + wid * 2;
  const float4* gsA = (const float4*)(gs + (wid * 2) * 960);
  const float4* gsB = gsA + 240;
  float accA[12], accB[12];
  #pragma unroll
  for (int c = 0; c < 12; c++){ accA[c] = 0.f; accB[c] = 0.f; }
  const float* wp = w_t + p;
  float wbuf[8];
  #pragma unroll
  for (int s = 0; s < 8; s++) wbuf[s] = wp[(size_t)s * PW_];
  #pragma unroll 8
  for (int j = 0; j < J_; j++){
    float w = wbuf[j & 7];
    if (j + 8 < J_) wbuf[j & 7] = wp[(size_t)(j + 8) * PW_];
    float4 a0 = gsA[j * 3], a1 = gsA[j * 3 + 1], a2 = gsA[j * 3 + 2];
    float4 c0 = gsB[j * 3], c1 = gsB[j * 3 + 1], c2 = gsB[j * 3 + 2];
    accA[0]  = fmaf(w, a0.x, accA[0]);  accA[1]  = fmaf(w, a0.y, accA[1]);
    accA[2]  = fmaf(w, a0.z, accA[2]);  accA[3]  = fmaf(w, a0.w, accA[3]);
    accA[4]  = fmaf(w, a1.x, accA[4]);  accA[5]  = fmaf(w, a1.y, accA[5]);
    accA[6]  = fmaf(w, a1.z, accA[6]);  accA[7]  = fmaf(w, a1.w, accA[7]);
    accA[8]  = fmaf(w, a2.x, accA[8]);  accA[9]  = fmaf(w, a2.y, accA[9]);
    accA[10] = fmaf(w, a2.z, accA[10]); accA[11] = fmaf(w, a2.w, accA[11]);
    accB[0]  = fmaf(w, c0.x, accB[0]);  accB[1]  = fmaf(w, c0.y, accB[1]);
    accB[2]  = fmaf(w, c0.z, accB[2]);  accB[3]  = fmaf(w, c0.w, accB[3]);
    accB[4]  = fmaf(w, c1.x, accB[4]);  accB[5]  = fmaf(w, c1.y, accB[5]);
    accB[6]  = fmaf(w, c1.z, accB[6]);  accB[7]  = fmaf(w, c1.w, accB[7]);
    accB[8]  = fmaf(w, c2.x, accB[8]);  accB[9]  = fmaf(w, c2.y, accB[9]);
    accB[10] = fmaf(w, c2.z, accB[10]); accB[11] = fmaf(w, c2.w, accB[11]);
  }
  bool vp = p < P_;
  float vx = 0.f, vy = 0.f, vz = 0.f;
  if (vp){ vx = rest[p * 3]; vy = rest[p * 3 + 1]; vz = rest[p * 3 + 2]; }
  float srs[3], srm[3];
  #pragma unroll
  for (int x = 0; x < 3; x++){ srs[x] = rstd[x]; srm[x] = rmean[x]; }
  float lsum = 0.f;
  if (vp){
    size_t baseA = ((size_t)bA * P_ + p) * 3;
    size_t baseB = baseA + (size_t)P_ * 3;
    #pragma unroll
    for (int x = 0; x < 3; x++){
      float det = out[1 + baseA + x];
      for (int s = 0; s < nst; s++) det += stg[(size_t)s * STG_ + baseA + x];
      float v = fmaf(accA[x*4+0], vx, fmaf(accA[x*4+1], vy, fmaf(accA[x*4+2], vz, accA[x*4+3])));
      v += fmaf(det, srs[x], srm[x]);
      lsum += fabsf(in_pc[baseA + x] - v);
      out[1 + baseA + x] = v;
    }
    #pragma unroll
    for (int x = 0; x < 3; x++){
      float det = out[1 + baseB + x];
      for (int s = 0; s < nst; s++) det += stg[(size_t)s * STG_ + baseB + x];
      float v = fmaf(accB[x*4+0], vx, fmaf(accB[x*4+1], vy, fmaf(accB[x*4+2], vz, accB[x*4+3])));
      v += fmaf(det, srs[x], srm[x]);
      lsum += fabsf(in_pc[baseB + x] - v);
      out[1 + baseB + x] = v;
    }
  }
  #pragma unroll
  for (int off = 32; off; off >>= 1) lsum += __shfl_xor(lsum, off);
  if (lane == 0) red[wid] = lsum;
  __syncthreads();
  if (t == 0) atomicAdd(&lacc[0], red[0] + red[1] + red[2] + red[3]);
}

// ---- K6: finalize scalar loss
__global__ void k_finalize(const float* __restrict__ lacc, float* __restrict__ out){
  if (threadIdx.x == 0 && blockIdx.x == 0){
    float loss = lacc[0] * (1.f / 2356416.f) + 1e-4f * (lacc[1] * (1.f / 12518460.f));
    out[0] = loss;
  }
}

extern "C" void kernel_launch(void* const* d_in, const int* in_sizes, int n_in,
                              void* d_out, int out_size, void* d_ws, size_t ws_size,
                              hipStream_t stream){
  const float* in_pc = (const float*)d_in[0];
  const float* rest  = (const float*)d_in[2];
  const float* skin  = (const float*)d_in[3];
  const float* mwl   = (const float*)d_in[4];
  const float* query = (const float*)d_in[5];
  const float* cps   = (const float*)d_in[6];
  const float* cpm   = (const float*)d_in[7];
  const float* cts   = (const float*)d_in[8];
  const float* ctm   = (const float*)d_in[9];
  const float* W1    = (const float*)d_in[10];
  const float* b1    = (const float*)d_in[11];
  const float* W2    = (const float*)d_in[12];
  const float* b2    = (const float*)d_in[13];
  const float* tm    = (const float*)d_in[14];
  const float* Wd    = (const float*)d_in[15];
  const float* bd    = (const float*)d_in[16];
  const float* DPSD  = (const float*)d_in[17];
  const float* rstd  = (const float*)d_in[18];
  const float* rmean = (const float*)d_in[19];
  float* out = (float*)d_out;

  float* ws   = (float*)d_ws;
  float* G    = ws;                 // 61440
  float* dk_t = G + 61440;          // 21760
  float* lacc = dk_t + 21760;       // 64 (pad)
  float* tm_t = lacc + 64;          // 385024
  float* w_t  = tm_t + 385024;      // 983040
  float* un   = w_t + 983040;       // union: part (94*24576=2310144) then stg0 (2356416)
  // part is dead before k_detail writes stg0 -> alias them.

  size_t have = ws_size / 4;
  int nqh = (have >= (size_t)(1451328 + 2356416)) ? 2 : 1;
  int qn = Q_ / nqh;                // 340 / 170

  k_prep    <<<1567, 256, 0, stream>>>(query, mwl, tm, W1, b1, W2, b2,
                                       cps, cpm, cts, ctm, skin,
                                       G, tm_t, w_t, lacc);
  k_dkey    <<<dim3(6, 94), 256, 0, stream>>>(tm_t, Wd, un);
  k_dkred   <<<680, 256, 0, stream>>>(un, bd, dk_t, 94);
  k_detail  <<<dim3(576, nqh), 256, 0, stream>>>(DPSD, dk_t, un, out, lacc, qn);
  k_skin    <<<dim3(192, 8), 256, 0, stream>>>(G, w_t, rest, in_pc, un, rstd, rmean,
                                               out, lacc, nqh - 1);
  k_finalize<<<1, 64, 0, stream>>>(lacc, out);
}

// Round 4
// 296.928 us; speedup vs baseline: 1.5260x; 1.0452x over previous
//
#include <hip/hip_runtime.h>

#define B_   64
#define P_   12273
#define J_   80
#define MOT_ 94
#define K_   64
#define H_   128
#define Q_   340      // NB*WN
#define NE_  36819    // P*3
#define MK_  6016     // MOT*K
#define PW_  12288    // padded P for w_t rows
#define STG_ 2356416  // B_*NE_ floats per staging buffer

typedef float v4f  __attribute__((ext_vector_type(4)));
typedef float v8f  __attribute__((ext_vector_type(8)));
typedef float v16f __attribute__((ext_vector_type(16)));
#define AS4 __attribute__((address_space(4)))

__device__ __forceinline__ const AS4 float* unif(const float* p){
  return (const AS4 float*)(unsigned long long)p;
}
__device__ __forceinline__ const AS4 v4f* univ4(const float* p){
  return (const AS4 v4f*)(unsigned long long)p;
}
__device__ __forceinline__ const AS4 v16f* univ16(const float* p){
  return (const AS4 v16f*)(unsigned long long)p;
}

// ---- K1 "prep": fieldnet + tm transpose + skin transpose + lacc init
__global__ __launch_bounds__(256) void k_prep(
    const float* __restrict__ query, const float* __restrict__ mwl,
    const float* __restrict__ tm,    const float* __restrict__ W1,
    const float* __restrict__ b1,    const float* __restrict__ W2,
    const float* __restrict__ b2,    const float* __restrict__ cps,
    const float* __restrict__ cpm,   const float* __restrict__ cts,
    const float* __restrict__ ctm,   const float* __restrict__ skin,
    float* __restrict__ G,           float* __restrict__ tm_t,
    float* __restrict__ w_t,         float* __restrict__ lacc)
{
  __shared__ float smem[80 * 65];
  int blk = blockIdx.x;
  int t = threadIdx.x;
  if (blk < 1280){
    int lane = t & 63;
    int wid = __builtin_amdgcn_readfirstlane(t >> 6);
    int bj = blk * 4 + wid;
    int b = bj / J_, l = bj - b * J_;
    float* hs = smem + wid * 80;
    float acc = 0.f;
    const AS4 float* mp = unif(mwl + l * MOT_);
    const float* tp = tm + (size_t)b * MK_ + lane;
    float tbuf[4];
    #pragma unroll
    for (int s = 0; s < 4; s++) tbuf[s] = tp[s * K_];
    #pragma unroll 4
    for (int j = 0; j < MOT_; j++){
      float tv = tbuf[j & 3];
      if (j + 4 < MOT_) tbuf[j & 3] = tp[(j + 4) * K_];
      float w = mp[j]; w = w > 0.f ? w : 0.f;
      acc = fmaf(w, tv, acc);
    }
    hs[3 + lane] = acc;
    if (lane < 3) hs[lane] = query[(size_t)bj * 3 + lane];
    __syncthreads();
    float a1 = b1[lane], a2 = b1[lane + 64];
    float wa[4], wb[4];
    #pragma unroll
    for (int s = 0; s < 4; s++){
      wa[s] = W1[s * H_ + lane];
      wb[s] = W1[s * H_ + 64 + lane];
    }
    #pragma unroll 4
    for (int i = 0; i < 67; i++){
      float hv = hs[i];
      float va = wa[i & 3], vb = wb[i & 3];
      if (i + 4 < 67){
        wa[i & 3] = W1[(i + 4) * H_ + lane];
        wb[i & 3] = W1[(i + 4) * H_ + 64 + lane];
      }
      a1 = fmaf(hv, va, a1);
      a2 = fmaf(hv, vb, a2);
    }
    a1 = a1 > 0.f ? a1 : 0.f;
    a2 = a2 > 0.f ? a2 : 0.f;
    const AS4 float* b2c = unif(b2);
    float rt[6];
    #pragma unroll
    for (int o = 0; o < 6; o++){
      float po = fmaf(a1, W2[lane * 6 + o], a2 * W2[(lane + 64) * 6 + o]);
      #pragma unroll
      for (int off = 32; off; off >>= 1) po += __shfl_xor(po, off);
      rt[o] = po + b2c[o];
    }
    const float D2R = 0.017453292519943295f;
    float ax = fmaf(rt[0], cps[0], cpm[0]) * D2R;
    float ay = fmaf(rt[1], cps[1], cpm[1]) * D2R;
    float az = fmaf(rt[2], cps[2], cpm[2]) * D2R;
    float tx = fmaf(hs[0] + rt[3], cts[0], ctm[0]);
    float ty = fmaf(hs[1] + rt[4], cts[1], ctm[1]);
    float tz = fmaf(hs[2] + rt[5], cts[2], ctm[2]);
    float sx, cx, sy, cy, sz, cz;
    sincosf(ax, &sx, &cx); sincosf(ay, &sy, &cy); sincosf(az, &sz, &cz);
    if (lane == 0){
      float4 r0 = make_float4(cz*cy, cz*sy*sx - sz*cx, cz*sy*cx + sz*sx, tx);
      float4 r1 = make_float4(sz*cy, sz*sy*sx + cz*cx, sz*sy*cx - cz*sx, ty);
      float4 r2 = make_float4(-sy,   cy*sx,            cy*cx,            tz);
      float4* g = (float4*)(G + (size_t)bj * 12);
      g[0] = r0; g[1] = r1; g[2] = r2;
    }
  } else if (blk < 1374){
    int m0 = (blk - 1280) * 64;
    int ml = t & 63, g = t >> 6;
    #pragma unroll
    for (int r = 0; r < 16; r++){
      int b = g * 16 + r;
      smem[ml * 65 + b] = tm[(size_t)b * MK_ + m0 + ml];
    }
    __syncthreads();
    int bl = t & 63;
    #pragma unroll
    for (int r = 0; r < 16; r++){
      int m = g * 16 + r;
      tm_t[(size_t)(m0 + m) * 64 + bl] = smem[m * 65 + bl];
    }
  } else if (blk < 1566){
    int p0 = (blk - 1374) * 64;
    #pragma unroll
    for (int k = 0; k < 20; k++){
      int idx = k * 256 + t;
      int pl = idx / 80, j = idx - pl * 80;
      int p = p0 + pl;
      smem[j * 65 + pl] = (p < P_) ? skin[(size_t)p * J_ + j] : 0.f;
    }
    __syncthreads();
    #pragma unroll
    for (int k = 0; k < 20; k++){
      int idx = k * 256 + t;
      int j = idx >> 6, pl = idx & 63;
      w_t[(size_t)j * PW_ + p0 + pl] = smem[j * 65 + pl];
    }
  } else {
    if (t < 2) lacc[t] = 0.f;
  }
}

// ---- K2: detailkey partial GEMM. grid (6, 94). Private part slices, no atomics.
__global__ __launch_bounds__(256) void k_dkey(
    const float* __restrict__ tm_t, const float* __restrict__ Wd,
    float* __restrict__ part)
{
  int t = threadIdx.x;
  int lane = t & 63;
  int wid = __builtin_amdgcn_readfirstlane(t >> 6);
  int qt = blockIdx.x;
  int q = qt * 64 + lane;
  bool vq = q < Q_;
  int m0 = blockIdx.y * 64;
  const AS4 v16f* tr = univ16(tm_t);
  float acc[16];
  #pragma unroll
  for (int i = 0; i < 16; i++) acc[i] = 0.f;
  float wbuf[4];
  #pragma unroll
  for (int i = 0; i < 4; i++)
    wbuf[i] = vq ? Wd[(size_t)(m0 + i) * Q_ + q] : 0.f;
  v16f tb0 = tr[(size_t)(m0 + 0) * 4 + wid];
  v16f tb1 = tr[(size_t)(m0 + 1) * 4 + wid];
  #pragma unroll 4
  for (int mm = 0; mm < 60; mm++){
    float wd = wbuf[mm & 3];
    wbuf[mm & 3] = vq ? Wd[(size_t)(m0 + mm + 4) * Q_ + q] : 0.f;
    v16f tv = tb0; tb0 = tb1;
    tb1 = tr[(size_t)(m0 + mm + 2) * 4 + wid];
    #pragma unroll
    for (int i = 0; i < 16; i++) acc[i] = fmaf(tv[i], wd, acc[i]);
  }
  #pragma unroll
  for (int mm = 60; mm < 64; mm++){
    float wd = wbuf[mm & 3];
    v16f tv = tb0; tb0 = tb1;
    if (mm < 62) tb1 = tr[(size_t)(m0 + mm + 2) * 4 + wid];
    #pragma unroll
    for (int i = 0; i < 16; i++) acc[i] = fmaf(tv[i], wd, acc[i]);
  }
  float* pb = part + ((size_t)blockIdx.y * 6 + qt) * 4096 + (size_t)(wid * 16) * 64;
  #pragma unroll
  for (int i = 0; i < 16; i++) pb[i * 64 + lane] = acc[i];
}

// ---- K3: reduce partials + bd -> dk_t[q*64+b]. 680 blocks, 8-way d-split per j.
__global__ __launch_bounds__(256) void k_dkred(
    const float* __restrict__ part, const float* __restrict__ bd,
    float* __restrict__ dk_t, int S)
{
  int t = threadIdx.x;
  int jj = blockIdx.x * 32 + (t >> 3);   // 680*32 = 21760 = B_*Q_ exactly
  int dl = t & 7;
  int b = jj / Q_, q = jj - b * Q_;
  int qt = q >> 6, ql = q & 63;
  const float* pp = part + (size_t)qt * 4096 + b * 64 + ql;
  float s = 0.f;
  for (int d = dl; d < S; d += 8) s += pp[(size_t)d * 6 * 4096];
  s += __shfl_xor(s, 1); s += __shfl_xor(s, 2); s += __shfl_xor(s, 4);
  if (dl == 0) dk_t[q * 64 + b] = bd[q] + s;
}

// ---- K4: detail einsum, 2 e x 16 b per thread. 320 wave-cycles of FMA per
//      5-q group covers the 5 uniform s_load_dwordx16 (~200cy) and the DPSD
//      ping-pong (issue->wait distance = 2 consumes ~ 640cy). grid (288, nqh).
__device__ __forceinline__ void dk_consume2(const AS4 v16f* dkv, int qa, int wid,
                                            const float* dc1, const float* dc2,
                                            float* acc1, float* acc2,
                                            float& sq1, float& sq2, bool doSq)
{
  #pragma unroll
  for (int qi = 0; qi < 5; qi++){
    v16f r = dkv[(size_t)(qa + qi) * 4 + wid];
    if (doSq){
      sq1 = fmaf(dc1[qi], dc1[qi], sq1);
      sq2 = fmaf(dc2[qi], dc2[qi], sq2);
    }
    #pragma unroll
    for (int i = 0; i < 16; i++){
      acc1[i] = fmaf(r[i], dc1[qi], acc1[i]);
      acc2[i] = fmaf(r[i], dc2[qi], acc2[i]);
    }
  }
}

__global__ __launch_bounds__(256) void k_detail(
    const float* __restrict__ DPSD, const float* __restrict__ dk_t,
    float* __restrict__ stg, float* __restrict__ out,
    float* __restrict__ lacc, int qn)
{
  int t = threadIdx.x;
  int lane = t & 63;
  int wid = __builtin_amdgcn_readfirstlane(t >> 6);  // 0..3
  int b0 = wid * 16;
  int e1 = blockIdx.x * 128 + lane;
  int e2 = e1 + 64;
  bool ve1 = e1 < NE_;
  bool ve2 = e2 < NE_;
  int q0 = blockIdx.y * qn;
  const AS4 v16f* dkv = univ16(dk_t);
  const float* Dp1 = DPSD + (ve1 ? e1 : 0);
  const float* Dp2 = DPSD + (ve2 ? e2 : 0);
  float acc1[16], acc2[16];
  #pragma unroll
  for (int i = 0; i < 16; i++){ acc1[i] = 0.f; acc2[i] = 0.f; }
  float sq1 = 0.f, sq2 = 0.f;
  bool doSq = (wid == 0);
  int ng = qn / 5;                  // 68 / 34 : always even
  float da1[5], da2[5], db1[5], db2[5];
  #pragma unroll
  for (int i = 0; i < 5; i++){
    da1[i] = Dp1[(size_t)(q0 + i) * NE_];
    da2[i] = Dp2[(size_t)(q0 + i) * NE_];
  }
  #pragma unroll
  for (int i = 0; i < 5; i++){
    db1[i] = Dp1[(size_t)(q0 + 5 + i) * NE_];
    db2[i] = Dp2[(size_t)(q0 + 5 + i) * NE_];
  }
  for (int g = 0; g + 2 < ng; g += 2){
    int qa = q0 + g * 5;
    float ta1[5], ta2[5], tb1[5], tb2[5];
    // issue both next-group prefetches before consuming (wait distance ~2 consumes)
    #pragma unroll
    for (int i = 0; i < 5; i++){
      ta1[i] = Dp1[(size_t)(qa + 10 + i) * NE_];
      ta2[i] = Dp2[(size_t)(qa + 10 + i) * NE_];
    }
    #pragma unroll
    for (int i = 0; i < 5; i++){
      tb1[i] = Dp1[(size_t)(qa + 15 + i) * NE_];
      tb2[i] = Dp2[(size_t)(qa + 15 + i) * NE_];
    }
    dk_consume2(dkv, qa,     wid, da1, da2, acc1, acc2, sq1, sq2, doSq);
    dk_consume2(dkv, qa + 5, wid, db1, db2, acc1, acc2, sq1, sq2, doSq);
    #pragma unroll
    for (int i = 0; i < 5; i++){ da1[i] = ta1[i]; da2[i] = ta2[i]; }
    #pragma unroll
    for (int i = 0; i < 5; i++){ db1[i] = tb1[i]; db2[i] = tb2[i]; }
  }
  dk_consume2(dkv, q0 + (ng - 2) * 5, wid, da1, da2, acc1, acc2, sq1, sq2, doSq);
  dk_consume2(dkv, q0 + (ng - 1) * 5, wid, db1, db2, acc1, acc2, sq1, sq2, doSq);
  bool toOut = (blockIdx.y + 1 == gridDim.y);
  {
    float* dst = (toOut ? (out + 1) : (stg + (size_t)blockIdx.y * STG_));
    if (ve1){
      #pragma unroll
      for (int i = 0; i < 16; i++)
        dst[(size_t)(b0 + i) * NE_ + e1] = acc1[i];
    }
    if (ve2){
      #pragma unroll
      for (int i = 0; i < 16; i++)
        dst[(size_t)(b0 + i) * NE_ + e2] = acc2[i];
    }
  }
  if (doSq){
    if (!ve1) sq1 = 0.f;
    if (!ve2) sq2 = 0.f;
    float sq = sq1 + sq2;
    #pragma unroll
    for (int off = 32; off; off >>= 1) sq += __shfl_xor(sq, off);
    if (lane == 0) atomicAdd(&lacc[1], sq);
  }
}

// ---- K5: LBS skinning, 2 p x 2 b per thread. G rows via uniform s_load
//      (no LDS); 96 wave-cycles of FMA per j covers the 6 s_load_dwordx4.
//      grid (96, 8).
__global__ __launch_bounds__(256) void k_skin(
    const float* __restrict__ G, const float* __restrict__ w_t,
    const float* __restrict__ rest, const float* __restrict__ in_pc,
    const float* __restrict__ stg, const float* __restrict__ rstd,
    const float* __restrict__ rmean,
    float* __restrict__ out, float* __restrict__ lacc, int nst)
{
  int t = threadIdx.x;
  int lane = t & 63;
  int wid = __builtin_amdgcn_readfirstlane(t >> 6);  // 0..3
  int p1 = blockIdx.x * 128 + lane;
  int p2 = p1 + 64;
  int bA = blockIdx.y * 8 + wid * 2;
  const AS4 v4f* gA = univ4(G + (size_t)bA * J_ * 12);
  const AS4 v4f* gB = univ4(G + ((size_t)bA + 1) * J_ * 12);
  float aA1[12], aA2[12], aB1[12], aB2[12];
  #pragma unroll
  for (int c = 0; c < 12; c++){ aA1[c] = 0.f; aA2[c] = 0.f; aB1[c] = 0.f; aB2[c] = 0.f; }
  const float* wp1 = w_t + p1;
  const float* wp2 = w_t + p2;
  #pragma unroll 2
  for (int j = 0; j < J_; j++){
    float w1 = wp1[(size_t)j * PW_];
    float w2 = wp2[(size_t)j * PW_];
    v4f a0 = gA[j * 3 + 0], a1 = gA[j * 3 + 1], a2 = gA[j * 3 + 2];
    v4f c0 = gB[j * 3 + 0], c1 = gB[j * 3 + 1], c2 = gB[j * 3 + 2];
    #pragma unroll
    for (int c = 0; c < 4; c++){
      aA1[c]     = fmaf(w1, a0[c], aA1[c]);
      aA1[4 + c] = fmaf(w1, a1[c], aA1[4 + c]);
      aA1[8 + c] = fmaf(w1, a2[c], aA1[8 + c]);
      aA2[c]     = fmaf(w2, a0[c], aA2[c]);
      aA2[4 + c] = fmaf(w2, a1[c], aA2[4 + c]);
      aA2[8 + c] = fmaf(w2, a2[c], aA2[8 + c]);
      aB1[c]     = fmaf(w1, c0[c], aB1[c]);
      aB1[4 + c] = fmaf(w1, c1[c], aB1[4 + c]);
      aB1[8 + c] = fmaf(w1, c2[c], aB1[8 + c]);
      aB2[c]     = fmaf(w2, c0[c], aB2[c]);
      aB2[4 + c] = fmaf(w2, c1[c], aB2[4 + c]);
      aB2[8 + c] = fmaf(w2, c2[c], aB2[8 + c]);
    }
  }
  float srs[3], srm[3];
  #pragma unroll
  for (int x = 0; x < 3; x++){ srs[x] = rstd[x]; srm[x] = rmean[x]; }
  float lsum = 0.f;
  bool vp1 = p1 < P_;
  bool vp2 = p2 < P_;
  if (vp1){
    float vx = rest[p1 * 3], vy = rest[p1 * 3 + 1], vz = rest[p1 * 3 + 2];
    size_t baseA = ((size_t)bA * P_ + p1) * 3;
    size_t baseB = baseA + (size_t)P_ * 3;
    #pragma unroll
    for (int x = 0; x < 3; x++){
      float det = out[1 + baseA + x];
      for (int s = 0; s < nst; s++) det += stg[(size_t)s * STG_ + baseA + x];
      float v = fmaf(aA1[x*4+0], vx, fmaf(aA1[x*4+1], vy, fmaf(aA1[x*4+2], vz, aA1[x*4+3])));
      v += fmaf(det, srs[x], srm[x]);
      lsum += fabsf(in_pc[baseA + x] - v);
      out[1 + baseA + x] = v;
    }
    #pragma unroll
    for (int x = 0; x < 3; x++){
      float det = out[1 + baseB + x];
      for (int s = 0; s < nst; s++) det += stg[(size_t)s * STG_ + baseB + x];
      float v = fmaf(aB1[x*4+0], vx, fmaf(aB1[x*4+1], vy, fmaf(aB1[x*4+2], vz, aB1[x*4+3])));
      v += fmaf(det, srs[x], srm[x]);
      lsum += fabsf(in_pc[baseB + x] - v);
      out[1 + baseB + x] = v;
    }
  }
  if (vp2){
    float vx = rest[p2 * 3], vy = rest[p2 * 3 + 1], vz = rest[p2 * 3 + 2];
    size_t baseA = ((size_t)bA * P_ + p2) * 3;
    size_t baseB = baseA + (size_t)P_ * 3;
    #pragma unroll
    for (int x = 0; x < 3; x++){
      float det = out[1 + baseA + x];
      for (int s = 0; s < nst; s++) det += stg[(size_t)s * STG_ + baseA + x];
      float v = fmaf(aA2[x*4+0], vx, fmaf(aA2[x*4+1], vy, fmaf(aA2[x*4+2], vz, aA2[x*4+3])));
      v += fmaf(det, srs[x], srm[x]);
      lsum += fabsf(in_pc[baseA + x] - v);
      out[1 + baseA + x] = v;
    }
    #pragma unroll
    for (int x = 0; x < 3; x++){
      float det = out[1 + baseB + x];
      for (int s = 0; s < nst; s++) det += stg[(size_t)s * STG_ + baseB + x];
      float v = fmaf(aB2[x*4+0], vx, fmaf(aB2[x*4+1], vy, fmaf(aB2[x*4+2], vz, aB2[x*4+3])));
      v += fmaf(det, srs[x], srm[x]);
      lsum += fabsf(in_pc[baseB + x] - v);
      out[1 + baseB + x] = v;
    }
  }
  #pragma unroll
  for (int off = 32; off; off >>= 1) lsum += __shfl_xor(lsum, off);
  __shared__ float red[4];
  if (lane == 0) red[wid] = lsum;
  __syncthreads();
  if (t == 0) atomicAdd(&lacc[0], red[0] + red[1] + red[2] + red[3]);
}

// ---- K6: finalize scalar loss
__global__ void k_finalize(const float* __restrict__ lacc, float* __restrict__ out){
  if (threadIdx.x == 0 && blockIdx.x == 0){
    float loss = lacc[0] * (1.f / 2356416.f) + 1e-4f * (lacc[1] * (1.f / 12518460.f));
    out[0] = loss;
  }
}

extern "C" void kernel_launch(void* const* d_in, const int* in_sizes, int n_in,
                              void* d_out, int out_size, void* d_ws, size_t ws_size,
                              hipStream_t stream){
  const float* in_pc = (const float*)d_in[0];
  const float* rest  = (const float*)d_in[2];
  const float* skin  = (const float*)d_in[3];
  const float* mwl   = (const float*)d_in[4];
  const float* query = (const float*)d_in[5];
  const float* cps   = (const float*)d_in[6];
  const float* cpm   = (const float*)d_in[7];
  const float* cts   = (const float*)d_in[8];
  const float* ctm   = (const float*)d_in[9];
  const float* W1    = (const float*)d_in[10];
  const float* b1    = (const float*)d_in[11];
  const float* W2    = (const float*)d_in[12];
  const float* b2    = (const float*)d_in[13];
  const float* tm    = (const float*)d_in[14];
  const float* Wd    = (const float*)d_in[15];
  const float* bd    = (const float*)d_in[16];
  const float* DPSD  = (const float*)d_in[17];
  const float* rstd  = (const float*)d_in[18];
  const float* rmean = (const float*)d_in[19];
  float* out = (float*)d_out;

  float* ws   = (float*)d_ws;
  float* G    = ws;                 // 61440
  float* dk_t = G + 61440;          // 21760
  float* lacc = dk_t + 21760;       // 64 (pad)
  float* tm_t = lacc + 64;          // 385024
  float* w_t  = tm_t + 385024;      // 983040
  float* un   = w_t + 983040;       // union: part (94*24576=2310144) then stg0 (2356416)
  // part is dead before k_detail writes stg0 -> alias them.

  size_t have = ws_size / 4;
  int nqh = (have >= (size_t)(1451328 + 2356416)) ? 2 : 1;
  int qn = Q_ / nqh;                // 340 / 170

  k_prep    <<<1567, 256, 0, stream>>>(query, mwl, tm, W1, b1, W2, b2,
                                       cps, cpm, cts, ctm, skin,
                                       G, tm_t, w_t, lacc);
  k_dkey    <<<dim3(6, 94), 256, 0, stream>>>(tm_t, Wd, un);
  k_dkred   <<<680, 256, 0, stream>>>(un, bd, dk_t, 94);
  k_detail  <<<dim3(288, nqh), 256, 0, stream>>>(DPSD, dk_t, un, out, lacc, qn);
  k_skin    <<<dim3(96, 8), 256, 0, stream>>>(G, w_t, rest, in_pc, un, rstd, rmean,
                                              out, lacc, nqh - 1);
  k_finalize<<<1, 64, 0, stream>>>(lacc, out);
}

// Round 6
// 289.483 us; speedup vs baseline: 1.5652x; 1.0257x over previous
//
#include <hip/hip_runtime.h>

#define B_   64
#define P_   12273
#define J_   80
#define MOT_ 94
#define K_   64
#define H_   128
#define Q_   340      // NB*WN
#define NE_  36819    // P*3
#define MK_  6016     // MOT*K
#define PW_  12288    // padded P for w_t rows
#define STG_ 2356416  // B_*NE_ floats per staging buffer

typedef float v4f  __attribute__((ext_vector_type(4)));
typedef float v16f __attribute__((ext_vector_type(16)));
#define AS4 __attribute__((address_space(4)))

__device__ __forceinline__ const AS4 float* unif(const float* p){
  return (const AS4 float*)(unsigned long long)p;
}
__device__ __forceinline__ const AS4 v4f* univ4(const float* p){
  return (const AS4 v4f*)(unsigned long long)p;
}
__device__ __forceinline__ const AS4 v16f* univ16(const float* p){
  return (const AS4 v16f*)(unsigned long long)p;
}

// ---- K1 "prep": fieldnet + tm transpose + skin transpose + lacc init
__global__ __launch_bounds__(256) void k_prep(
    const float* __restrict__ query, const float* __restrict__ mwl,
    const float* __restrict__ tm,    const float* __restrict__ W1,
    const float* __restrict__ b1,    const float* __restrict__ W2,
    const float* __restrict__ b2,    const float* __restrict__ cps,
    const float* __restrict__ cpm,   const float* __restrict__ cts,
    const float* __restrict__ ctm,   const float* __restrict__ skin,
    float* __restrict__ G,           float* __restrict__ tm_t,
    float* __restrict__ w_t,         float* __restrict__ lacc)
{
  __shared__ float smem[80 * 65];
  int blk = blockIdx.x;
  int t = threadIdx.x;
  if (blk < 1280){
    int lane = t & 63;
    int wid = __builtin_amdgcn_readfirstlane(t >> 6);
    int bj = blk * 4 + wid;
    int b = bj / J_, l = bj - b * J_;
    float* hs = smem + wid * 80;
    float acc = 0.f;
    const AS4 float* mp = unif(mwl + l * MOT_);
    const float* tp = tm + (size_t)b * MK_ + lane;
    float tbuf[4];
    #pragma unroll
    for (int s = 0; s < 4; s++) tbuf[s] = tp[s * K_];
    #pragma unroll 4
    for (int j = 0; j < MOT_; j++){
      float tv = tbuf[j & 3];
      if (j + 4 < MOT_) tbuf[j & 3] = tp[(j + 4) * K_];
      float w = mp[j]; w = w > 0.f ? w : 0.f;
      acc = fmaf(w, tv, acc);
    }
    hs[3 + lane] = acc;
    if (lane < 3) hs[lane] = query[(size_t)bj * 3 + lane];
    __syncthreads();
    float a1 = b1[lane], a2 = b1[lane + 64];
    float wa[4], wb[4];
    #pragma unroll
    for (int s = 0; s < 4; s++){
      wa[s] = W1[s * H_ + lane];
      wb[s] = W1[s * H_ + 64 + lane];
    }
    #pragma unroll 4
    for (int i = 0; i < 67; i++){
      float hv = hs[i];
      float va = wa[i & 3], vb = wb[i & 3];
      if (i + 4 < 67){
        wa[i & 3] = W1[(i + 4) * H_ + lane];
        wb[i & 3] = W1[(i + 4) * H_ + 64 + lane];
      }
      a1 = fmaf(hv, va, a1);
      a2 = fmaf(hv, vb, a2);
    }
    a1 = a1 > 0.f ? a1 : 0.f;
    a2 = a2 > 0.f ? a2 : 0.f;
    const AS4 float* b2c = unif(b2);
    float rt[6];
    #pragma unroll
    for (int o = 0; o < 6; o++){
      float po = fmaf(a1, W2[lane * 6 + o], a2 * W2[(lane + 64) * 6 + o]);
      #pragma unroll
      for (int off = 32; off; off >>= 1) po += __shfl_xor(po, off);
      rt[o] = po + b2c[o];
    }
    const float D2R = 0.017453292519943295f;
    float ax = fmaf(rt[0], cps[0], cpm[0]) * D2R;
    float ay = fmaf(rt[1], cps[1], cpm[1]) * D2R;
    float az = fmaf(rt[2], cps[2], cpm[2]) * D2R;
    float tx = fmaf(hs[0] + rt[3], cts[0], ctm[0]);
    float ty = fmaf(hs[1] + rt[4], cts[1], ctm[1]);
    float tz = fmaf(hs[2] + rt[5], cts[2], ctm[2]);
    float sx, cx, sy, cy, sz, cz;
    sincosf(ax, &sx, &cx); sincosf(ay, &sy, &cy); sincosf(az, &sz, &cz);
    if (lane == 0){
      float4 r0 = make_float4(cz*cy, cz*sy*sx - sz*cx, cz*sy*cx + sz*sx, tx);
      float4 r1 = make_float4(sz*cy, sz*sy*sx + cz*cx, sz*sy*cx - cz*sx, ty);
      float4 r2 = make_float4(-sy,   cy*sx,            cy*cx,            tz);
      float4* g = (float4*)(G + (size_t)bj * 12);
      g[0] = r0; g[1] = r1; g[2] = r2;
    }
  } else if (blk < 1374){
    int m0 = (blk - 1280) * 64;
    int ml = t & 63, g = t >> 6;
    #pragma unroll
    for (int r = 0; r < 16; r++){
      int b = g * 16 + r;
      smem[ml * 65 + b] = tm[(size_t)b * MK_ + m0 + ml];
    }
    __syncthreads();
    int bl = t & 63;
    #pragma unroll
    for (int r = 0; r < 16; r++){
      int m = g * 16 + r;
      tm_t[(size_t)(m0 + m) * 64 + bl] = smem[m * 65 + bl];
    }
  } else if (blk < 1566){
    int p0 = (blk - 1374) * 64;
    #pragma unroll
    for (int k = 0; k < 20; k++){
      int idx = k * 256 + t;
      int pl = idx / 80, j = idx - pl * 80;
      int p = p0 + pl;
      smem[j * 65 + pl] = (p < P_) ? skin[(size_t)p * J_ + j] : 0.f;
    }
    __syncthreads();
    #pragma unroll
    for (int k = 0; k < 20; k++){
      int idx = k * 256 + t;
      int j = idx >> 6, pl = idx & 63;
      w_t[(size_t)j * PW_ + p0 + pl] = smem[j * 65 + pl];
    }
  } else {
    if (t < 2) lacc[t] = 0.f;
  }
}

// ---- K2: detailkey partial GEMM. grid (6, 94). Private part slices, no atomics.
__global__ __launch_bounds__(256) void k_dkey(
    const float* __restrict__ tm_t, const float* __restrict__ Wd,
    float* __restrict__ part)
{
  int t = threadIdx.x;
  int lane = t & 63;
  int wid = __builtin_amdgcn_readfirstlane(t >> 6);
  int qt = blockIdx.x;
  int q = qt * 64 + lane;
  bool vq = q < Q_;
  int m0 = blockIdx.y * 64;
  const AS4 v16f* tr = univ16(tm_t);
  float acc[16];
  #pragma unroll
  for (int i = 0; i < 16; i++) acc[i] = 0.f;
  float wbuf[4];
  #pragma unroll
  for (int i = 0; i < 4; i++)
    wbuf[i] = vq ? Wd[(size_t)(m0 + i) * Q_ + q] : 0.f;
  v16f tb0 = tr[(size_t)(m0 + 0) * 4 + wid];
  v16f tb1 = tr[(size_t)(m0 + 1) * 4 + wid];
  #pragma unroll 4
  for (int mm = 0; mm < 60; mm++){
    float wd = wbuf[mm & 3];
    wbuf[mm & 3] = vq ? Wd[(size_t)(m0 + mm + 4) * Q_ + q] : 0.f;
    v16f tv = tb0; tb0 = tb1;
    tb1 = tr[(size_t)(m0 + mm + 2) * 4 + wid];
    #pragma unroll
    for (int i = 0; i < 16; i++) acc[i] = fmaf(tv[i], wd, acc[i]);
  }
  #pragma unroll
  for (int mm = 60; mm < 64; mm++){
    float wd = wbuf[mm & 3];
    v16f tv = tb0; tb0 = tb1;
    if (mm < 62) tb1 = tr[(size_t)(m0 + mm + 2) * 4 + wid];
    #pragma unroll
    for (int i = 0; i < 16; i++) acc[i] = fmaf(tv[i], wd, acc[i]);
  }
  float* pb = part + ((size_t)blockIdx.y * 6 + qt) * 4096 + (size_t)(wid * 16) * 64;
  #pragma unroll
  for (int i = 0; i < 16; i++) pb[i * 64 + lane] = acc[i];
}

// ---- K3: reduce partials + bd -> dk_t[q*64+b]. 680 blocks, 8-way d-split per j.
__global__ __launch_bounds__(256) void k_dkred(
    const float* __restrict__ part, const float* __restrict__ bd,
    float* __restrict__ dk_t, int S)
{
  int t = threadIdx.x;
  int jj = blockIdx.x * 32 + (t >> 3);   // 680*32 = 21760 = B_*Q_ exactly
  int dl = t & 7;
  int b = jj / Q_, q = jj - b * Q_;
  int qt = q >> 6, ql = q & 63;
  const float* pp = part + (size_t)qt * 4096 + b * 64 + ql;
  float s = 0.f;
  for (int d = dl; d < S; d += 8) s += pp[(size_t)d * 6 * 4096];
  s += __shfl_xor(s, 1); s += __shfl_xor(s, 2); s += __shfl_xor(s, 4);
  if (dl == 0) dk_t[q * 64 + b] = bd[q] + s;
}

// ---- K4: detail einsum v4. DPSD staged via LDS double-buffer (4 q rows x
//      256 e per tile; reg-staged, loads issued at tile start, ds_write at
//      tile end, one barrier per tile). dk rows in SGPR via explicit 2-pair
//      ping-pong (s_load issued 2 q = 256 FMA-cycles ahead of use).
//      Thread: 4 contiguous e x 16 b. Grid (144, nqh); q-chunks of QSTEP.
template<bool TAIL>
__device__ __forceinline__ void cons_q(const v16f& dk, const v4f& d,
                                       v4f* acc, float& sq, bool doSq, int e4)
{
  if (doSq){
    #pragma unroll
    for (int c = 0; c < 4; c++)
      if (!TAIL || (e4 + c) < NE_) sq = fmaf(d[c], d[c], sq);
  }
  #pragma unroll
  for (int i = 0; i < 16; i++){
    #pragma unroll
    for (int c = 0; c < 4; c++)
      acc[i][c] = fmaf(dk[i], d[c], acc[i][c]);
  }
}

template<bool TAIL>
__device__ __forceinline__ void detail_body(
    const float* __restrict__ DPSD, const float* __restrict__ dk_t,
    float* __restrict__ stg, float* __restrict__ out,
    float* __restrict__ lacc, int QSTEP, float* sbuf)
{
  int t = threadIdx.x;
  int lane = t & 63;
  int wid = __builtin_amdgcn_readfirstlane(t >> 6);  // 0..3
  int b0 = wid * 16;
  int e4 = blockIdx.x * 256 + lane * 4;
  int q0 = blockIdx.y * QSTEP;
  int qn = min(QSTEP, Q_ - q0);      // always a multiple of 4
  int nt = qn >> 2;
  const AS4 v16f* tr = univ16(dk_t);
  bool doSq = (wid == 0);
  v4f acc[16];
  #pragma unroll
  for (int i = 0; i < 16; i++){
    #pragma unroll
    for (int c = 0; c < 4; c++) acc[i][c] = 0.f;
  }
  float sq = 0.f;
  float nx0, nx1, nx2, nx3;
  // prologue: stage tile 0 (wave w loads row w of the tile)
  {
    size_t base = (size_t)(q0 + wid) * NE_;
    int ea = e4, eb = e4 + 1, ec = e4 + 2, ed = e4 + 3;
    if (TAIL){
      ea = ea < NE_ ? ea : NE_ - 1; eb = eb < NE_ ? eb : NE_ - 1;
      ec = ec < NE_ ? ec : NE_ - 1; ed = ed < NE_ ? ed : NE_ - 1;
    }
    nx0 = DPSD[base + ea]; nx1 = DPSD[base + eb];
    nx2 = DPSD[base + ec]; nx3 = DPSD[base + ed];
    v4f vv = {nx0, nx1, nx2, nx3};
    *(v4f*)(sbuf + wid * 256 + lane * 4) = vv;
  }
  __syncthreads();
  v16f dkA0 = tr[(size_t)(q0 + 0) * 4 + wid];
  v16f dkA1 = tr[(size_t)(q0 + 1) * 4 + wid];
  int cur = 0;
  for (int tt = 0; tt < nt; tt++){
    int qb = q0 + tt * 4;
    bool more = (tt + 1 < nt);
    if (more){
      size_t base = (size_t)(qb + 4 + wid) * NE_;
      int ea = e4, eb = e4 + 1, ec = e4 + 2, ed = e4 + 3;
      if (TAIL){
        ea = ea < NE_ ? ea : NE_ - 1; eb = eb < NE_ ? eb : NE_ - 1;
        ec = ec < NE_ ? ec : NE_ - 1; ed = ed < NE_ ? ed : NE_ - 1;
      }
      nx0 = DPSD[base + ea]; nx1 = DPSD[base + eb];
      nx2 = DPSD[base + ec]; nx3 = DPSD[base + ed];
    }
    const float* sb = sbuf + cur * 1024;
    v16f dkB0 = tr[(size_t)(qb + 2) * 4 + wid];
    v16f dkB1 = tr[(size_t)(qb + 3) * 4 + wid];
    v4f d0 = *(const v4f*)(sb + 0 * 256 + lane * 4);
    v4f d1 = *(const v4f*)(sb + 1 * 256 + lane * 4);
    cons_q<TAIL>(dkA0, d0, acc, sq, doSq, e4);
    cons_q<TAIL>(dkA1, d1, acc, sq, doSq, e4);
    int qnx = min(qb + 4, Q_ - 2);
    dkA0 = tr[(size_t)(qnx + 0) * 4 + wid];
    dkA1 = tr[(size_t)(qnx + 1) * 4 + wid];
    v4f d2 = *(const v4f*)(sb + 2 * 256 + lane * 4);
    v4f d3 = *(const v4f*)(sb + 3 * 256 + lane * 4);
    cons_q<TAIL>(dkB0, d2, acc, sq, doSq, e4);
    cons_q<TAIL>(dkB1, d3, acc, sq, doSq, e4);
    if (more){
      v4f vv = {nx0, nx1, nx2, nx3};
      *(v4f*)(sbuf + (cur ^ 1) * 1024 + wid * 256 + lane * 4) = vv;
    }
    __syncthreads();
    cur ^= 1;
  }
  bool toOut = (blockIdx.y + 1 == gridDim.y);
  float* dst = toOut ? (out + 1) : (stg + (size_t)blockIdx.y * STG_);
  #pragma unroll
  for (int i = 0; i < 16; i++){
    size_t rb = (size_t)(b0 + i) * NE_;
    #pragma unroll
    for (int c = 0; c < 4; c++){
      int e = e4 + c;
      if (!TAIL || e < NE_) dst[rb + e] = acc[i][c];
    }
  }
  if (doSq){
    #pragma unroll
    for (int off = 32; off; off >>= 1) sq += __shfl_xor(sq, off);
    if (lane == 0) atomicAdd(&lacc[1], sq);
  }
}

__global__ __launch_bounds__(256) void k_detail(
    const float* __restrict__ DPSD, const float* __restrict__ dk_t,
    float* __restrict__ stg, float* __restrict__ out,
    float* __restrict__ lacc, int QSTEP)
{
  __shared__ float sbuf[2048];
  if (blockIdx.x == gridDim.x - 1)
    detail_body<true>(DPSD, dk_t, stg, out, lacc, QSTEP, sbuf);
  else
    detail_body<false>(DPSD, dk_t, stg, out, lacc, QSTEP, sbuf);
}

// ---- K5: LBS skinning v3. Grid (48, 32): all 4 waves of a block share ONE
//      b-pair (y) -> G scalar stream fetched once per block (4x less K$
//      pressure); explicit depth-2 SGPR ping-pong on G rows. Thread: 1 p, 2 b.
__global__ __launch_bounds__(256) void k_skin(
    const float* __restrict__ G, const float* __restrict__ w_t,
    const float* __restrict__ rest, const float* __restrict__ in_pc,
    const float* __restrict__ stg, const float* __restrict__ rstd,
    const float* __restrict__ rmean,
    float* __restrict__ out, float* __restrict__ lacc, int nst)
{
  int t = threadIdx.x;
  int lane = t & 63;
  int wid = __builtin_amdgcn_readfirstlane(t >> 6);  // p-chunk 0..3
  int p = blockIdx.x * 256 + wid * 64 + lane;
  int bA = blockIdx.y * 2;
  const AS4 v4f* gA = univ4(G + (size_t)bA * J_ * 12);
  const AS4 v4f* gB = univ4(G + ((size_t)bA + 1) * J_ * 12);
  float accA[12], accB[12];
  #pragma unroll
  for (int c = 0; c < 12; c++){ accA[c] = 0.f; accB[c] = 0.f; }
  const float* wp = w_t + p;
  v4f A0[2], A1[2], A2[2], B0[2], B1[2], B2[2];
  A0[0] = gA[0]; A1[0] = gA[1]; A2[0] = gA[2];
  B0[0] = gB[0]; B1[0] = gB[1]; B2[0] = gB[2];
  #pragma unroll 2
  for (int j = 0; j < J_; j++){
    int cs = j & 1, ns = cs ^ 1;
    if (j + 1 < J_){
      A0[ns] = gA[(j + 1) * 3 + 0];
      A1[ns] = gA[(j + 1) * 3 + 1];
      A2[ns] = gA[(j + 1) * 3 + 2];
      B0[ns] = gB[(j + 1) * 3 + 0];
      B1[ns] = gB[(j + 1) * 3 + 1];
      B2[ns] = gB[(j + 1) * 3 + 2];
    }
    float w = wp[(size_t)j * PW_];
    #pragma unroll
    for (int c = 0; c < 4; c++){
      accA[c]     = fmaf(w, A0[cs][c], accA[c]);
      accA[4 + c] = fmaf(w, A1[cs][c], accA[4 + c]);
      accA[8 + c] = fmaf(w, A2[cs][c], accA[8 + c]);
      accB[c]     = fmaf(w, B0[cs][c], accB[c]);
      accB[4 + c] = fmaf(w, B1[cs][c], accB[4 + c]);
      accB[8 + c] = fmaf(w, B2[cs][c], accB[8 + c]);
    }
  }
  float srs[3], srm[3];
  #pragma unroll
  for (int x = 0; x < 3; x++){ srs[x] = rstd[x]; srm[x] = rmean[x]; }
  float lsum = 0.f;
  bool vp = p < P_;
  if (vp){
    float vx = rest[p * 3], vy = rest[p * 3 + 1], vz = rest[p * 3 + 2];
    size_t baseA = ((size_t)bA * P_ + p) * 3;
    size_t baseB = baseA + (size_t)P_ * 3;
    #pragma unroll
    for (int x = 0; x < 3; x++){
      float det = out[1 + baseA + x];
      for (int s = 0; s < nst; s++) det += stg[(size_t)s * STG_ + baseA + x];
      float v = fmaf(accA[x*4+0], vx, fmaf(accA[x*4+1], vy, fmaf(accA[x*4+2], vz, accA[x*4+3])));
      v += fmaf(det, srs[x], srm[x]);
      lsum += fabsf(in_pc[baseA + x] - v);
      out[1 + baseA + x] = v;
    }
    #pragma unroll
    for (int x = 0; x < 3; x++){
      float det = out[1 + baseB + x];
      for (int s = 0; s < nst; s++) det += stg[(size_t)s * STG_ + baseB + x];
      float v = fmaf(accB[x*4+0], vx, fmaf(accB[x*4+1], vy, fmaf(accB[x*4+2], vz, accB[x*4+3])));
      v += fmaf(det, srs[x], srm[x]);
      lsum += fabsf(in_pc[baseB + x] - v);
      out[1 + baseB + x] = v;
    }
  }
  #pragma unroll
  for (int off = 32; off; off >>= 1) lsum += __shfl_xor(lsum, off);
  __shared__ float red[4];
  if (lane == 0) red[wid] = lsum;
  __syncthreads();
  if (t == 0) atomicAdd(&lacc[0], red[0] + red[1] + red[2] + red[3]);
}

// ---- K6: finalize scalar loss
__global__ void k_finalize(const float* __restrict__ lacc, float* __restrict__ out){
  if (threadIdx.x == 0 && blockIdx.x == 0){
    float loss = lacc[0] * (1.f / 2356416.f) + 1e-4f * (lacc[1] * (1.f / 12518460.f));
    out[0] = loss;
  }
}

extern "C" void kernel_launch(void* const* d_in, const int* in_sizes, int n_in,
                              void* d_out, int out_size, void* d_ws, size_t ws_size,
                              hipStream_t stream){
  const float* in_pc = (const float*)d_in[0];
  const float* rest  = (const float*)d_in[2];
  const float* skin  = (const float*)d_in[3];
  const float* mwl   = (const float*)d_in[4];
  const float* query = (const float*)d_in[5];
  const float* cps   = (const float*)d_in[6];
  const float* cpm   = (const float*)d_in[7];
  const float* cts   = (const float*)d_in[8];
  const float* ctm   = (const float*)d_in[9];
  const float* W1    = (const float*)d_in[10];
  const float* b1    = (const float*)d_in[11];
  const float* W2    = (const float*)d_in[12];
  const float* b2    = (const float*)d_in[13];
  const float* tm    = (const float*)d_in[14];
  const float* Wd    = (const float*)d_in[15];
  const float* bd    = (const float*)d_in[16];
  const float* DPSD  = (const float*)d_in[17];
  const float* rstd  = (const float*)d_in[18];
  const float* rmean = (const float*)d_in[19];
  float* out = (float*)d_out;

  float* ws   = (float*)d_ws;
  float* G    = ws;                 // 61440
  float* dk_t = G + 61440;          // 21760
  float* lacc = dk_t + 21760;       // 64 (pad)
  float* tm_t = lacc + 64;          // 385024
  float* w_t  = tm_t + 385024;      // 983040
  float* un   = w_t + 983040;       // union: part (2310144) then stg chunks
  // part is dead before k_detail writes stg -> alias them.

  size_t have = ws_size / 4;
  const size_t base = 1451328;
  int nqh, QSTEP;
  if (have >= base + 3 * (size_t)STG_)      { nqh = 4; QSTEP = 88;  }
  else if (have >= base + (size_t)STG_)     { nqh = 2; QSTEP = 172; }
  else                                      { nqh = 1; QSTEP = 340; }

  k_prep    <<<1567, 256, 0, stream>>>(query, mwl, tm, W1, b1, W2, b2,
                                       cps, cpm, cts, ctm, skin,
                                       G, tm_t, w_t, lacc);
  k_dkey    <<<dim3(6, 94), 256, 0, stream>>>(tm_t, Wd, un);
  k_dkred   <<<680, 256, 0, stream>>>(un, bd, dk_t, 94);
  k_detail  <<<dim3(144, nqh), 256, 0, stream>>>(DPSD, dk_t, un, out, lacc, QSTEP);
  k_skin    <<<dim3(48, 32), 256, 0, stream>>>(G, w_t, rest, in_pc, un, rstd, rmean,
                                               out, lacc, nqh - 1);
  k_finalize<<<1, 64, 0, stream>>>(lacc, out);
}

// Round 7
// 286.086 us; speedup vs baseline: 1.5838x; 1.0119x over previous
//
#include <hip/hip_runtime.h>

#define B_   64
#define P_   12273
#define J_   80
#define MOT_ 94
#define K_   64
#define H_   128
#define Q_   340      // NB*WN
#define NE_  36819    // P*3
#define MK_  6016     // MOT*K
#define PW_  12288    // padded P for w_t rows
#define STG_ 2356416  // B_*NE_ floats per staging buffer

typedef float v4f  __attribute__((ext_vector_type(4)));
typedef float v16f __attribute__((ext_vector_type(16)));
#define AS4 __attribute__((address_space(4)))

__device__ __forceinline__ const AS4 float* unif(const float* p){
  return (const AS4 float*)(unsigned long long)p;
}
__device__ __forceinline__ const AS4 v4f* univ4(const float* p){
  return (const AS4 v4f*)(unsigned long long)p;
}
__device__ __forceinline__ const AS4 v16f* univ16(const float* p){
  return (const AS4 v16f*)(unsigned long long)p;
}

// ---- K1 "prep": fieldnet + tm transpose + skin transpose + lacc init.
//      G written pre-swizzled: G_sw[b>>1][j][ (b&1)*12 + 0..11 ]  (24/row)
//      so k_skin reads one contiguous 96B run per (b-pair, j).
__global__ __launch_bounds__(256) void k_prep(
    const float* __restrict__ query, const float* __restrict__ mwl,
    const float* __restrict__ tm,    const float* __restrict__ W1,
    const float* __restrict__ b1,    const float* __restrict__ W2,
    const float* __restrict__ b2,    const float* __restrict__ cps,
    const float* __restrict__ cpm,   const float* __restrict__ cts,
    const float* __restrict__ ctm,   const float* __restrict__ skin,
    float* __restrict__ G,           float* __restrict__ tm_t,
    float* __restrict__ w_t,         float* __restrict__ lacc)
{
  __shared__ float smem[80 * 65];
  int blk = blockIdx.x;
  int t = threadIdx.x;
  if (blk < 1280){
    int lane = t & 63;
    int wid = __builtin_amdgcn_readfirstlane(t >> 6);
    int bj = blk * 4 + wid;
    int b = bj / J_, l = bj - b * J_;
    float* hs = smem + wid * 80;
    float acc = 0.f;
    const AS4 float* mp = unif(mwl + l * MOT_);
    const float* tp = tm + (size_t)b * MK_ + lane;
    float tbuf[8];
    #pragma unroll
    for (int s = 0; s < 8; s++) tbuf[s] = tp[s * K_];
    #pragma unroll 8
    for (int j = 0; j < MOT_; j++){
      float tv = tbuf[j & 7];
      if (j + 8 < MOT_) tbuf[j & 7] = tp[(j + 8) * K_];
      float w = mp[j]; w = w > 0.f ? w : 0.f;
      acc = fmaf(w, tv, acc);
    }
    hs[3 + lane] = acc;
    if (lane < 3) hs[lane] = query[(size_t)bj * 3 + lane];
    __syncthreads();
    float a1 = b1[lane], a2 = b1[lane + 64];
    float wa[8], wb[8];
    #pragma unroll
    for (int s = 0; s < 8; s++){
      wa[s] = W1[s * H_ + lane];
      wb[s] = W1[s * H_ + 64 + lane];
    }
    #pragma unroll 8
    for (int i = 0; i < 67; i++){
      float hv = hs[i];
      float va = wa[i & 7], vb = wb[i & 7];
      if (i + 8 < 67){
        wa[i & 7] = W1[(i + 8) * H_ + lane];
        wb[i & 7] = W1[(i + 8) * H_ + 64 + lane];
      }
      a1 = fmaf(hv, va, a1);
      a2 = fmaf(hv, vb, a2);
    }
    a1 = a1 > 0.f ? a1 : 0.f;
    a2 = a2 > 0.f ? a2 : 0.f;
    const AS4 float* b2c = unif(b2);
    float rt[6];
    #pragma unroll
    for (int o = 0; o < 6; o++){
      float po = fmaf(a1, W2[lane * 6 + o], a2 * W2[(lane + 64) * 6 + o]);
      #pragma unroll
      for (int off = 32; off; off >>= 1) po += __shfl_xor(po, off);
      rt[o] = po + b2c[o];
    }
    const float D2R = 0.017453292519943295f;
    float ax = fmaf(rt[0], cps[0], cpm[0]) * D2R;
    float ay = fmaf(rt[1], cps[1], cpm[1]) * D2R;
    float az = fmaf(rt[2], cps[2], cpm[2]) * D2R;
    float tx = fmaf(hs[0] + rt[3], cts[0], ctm[0]);
    float ty = fmaf(hs[1] + rt[4], cts[1], ctm[1]);
    float tz = fmaf(hs[2] + rt[5], cts[2], ctm[2]);
    float sx, cx, sy, cy, sz, cz;
    sincosf(ax, &sx, &cx); sincosf(ay, &sy, &cy); sincosf(az, &sz, &cz);
    if (lane == 0){
      float4 r0 = make_float4(cz*cy, cz*sy*sx - sz*cx, cz*sy*cx + sz*sx, tx);
      float4 r1 = make_float4(sz*cy, sz*sy*sx + cz*cx, sz*sy*cx - cz*sx, ty);
      float4 r2 = make_float4(-sy,   cy*sx,            cy*cx,            tz);
      // swizzled: pair bp = b>>1, half = b&1
      size_t o = ((size_t)(b >> 1) * J_ + l) * 24 + (b & 1) * 12;
      float4* g = (float4*)(G + o);
      g[0] = r0; g[1] = r1; g[2] = r2;
    }
  } else if (blk < 1374){
    int m0 = (blk - 1280) * 64;
    int ml = t & 63, g = t >> 6;
    #pragma unroll
    for (int r = 0; r < 16; r++){
      int b = g * 16 + r;
      smem[ml * 65 + b] = tm[(size_t)b * MK_ + m0 + ml];
    }
    __syncthreads();
    int bl = t & 63;
    #pragma unroll
    for (int r = 0; r < 16; r++){
      int m = g * 16 + r;
      tm_t[(size_t)(m0 + m) * 64 + bl] = smem[m * 65 + bl];
    }
  } else if (blk < 1566){
    int p0 = (blk - 1374) * 64;
    #pragma unroll
    for (int k = 0; k < 20; k++){
      int idx = k * 256 + t;
      int pl = idx / 80, j = idx - pl * 80;
      int p = p0 + pl;
      smem[j * 65 + pl] = (p < P_) ? skin[(size_t)p * J_ + j] : 0.f;
    }
    __syncthreads();
    #pragma unroll
    for (int k = 0; k < 20; k++){
      int idx = k * 256 + t;
      int j = idx >> 6, pl = idx & 63;
      w_t[(size_t)j * PW_ + p0 + pl] = smem[j * 65 + pl];
    }
  } else {
    if (t < 2) lacc[t] = 0.f;
  }
}

// ---- K2: detailkey partial GEMM. grid (6, 94). Private part slices, no atomics.
__global__ __launch_bounds__(256) void k_dkey(
    const float* __restrict__ tm_t, const float* __restrict__ Wd,
    float* __restrict__ part)
{
  int t = threadIdx.x;
  int lane = t & 63;
  int wid = __builtin_amdgcn_readfirstlane(t >> 6);
  int qt = blockIdx.x;
  int q = qt * 64 + lane;
  bool vq = q < Q_;
  int m0 = blockIdx.y * 64;
  const AS4 v16f* tr = univ16(tm_t);
  float acc[16];
  #pragma unroll
  for (int i = 0; i < 16; i++) acc[i] = 0.f;
  float wbuf[4];
  #pragma unroll
  for (int i = 0; i < 4; i++)
    wbuf[i] = vq ? Wd[(size_t)(m0 + i) * Q_ + q] : 0.f;
  v16f tb0 = tr[(size_t)(m0 + 0) * 4 + wid];
  v16f tb1 = tr[(size_t)(m0 + 1) * 4 + wid];
  #pragma unroll 4
  for (int mm = 0; mm < 60; mm++){
    float wd = wbuf[mm & 3];
    wbuf[mm & 3] = vq ? Wd[(size_t)(m0 + mm + 4) * Q_ + q] : 0.f;
    v16f tv = tb0; tb0 = tb1;
    tb1 = tr[(size_t)(m0 + mm + 2) * 4 + wid];
    #pragma unroll
    for (int i = 0; i < 16; i++) acc[i] = fmaf(tv[i], wd, acc[i]);
  }
  #pragma unroll
  for (int mm = 60; mm < 64; mm++){
    float wd = wbuf[mm & 3];
    v16f tv = tb0; tb0 = tb1;
    if (mm < 62) tb1 = tr[(size_t)(m0 + mm + 2) * 4 + wid];
    #pragma unroll
    for (int i = 0; i < 16; i++) acc[i] = fmaf(tv[i], wd, acc[i]);
  }
  float* pb = part + ((size_t)blockIdx.y * 6 + qt) * 4096 + (size_t)(wid * 16) * 64;
  #pragma unroll
  for (int i = 0; i < 16; i++) pb[i * 64 + lane] = acc[i];
}

// ---- K3: reduce partials + bd. Output layout swizzled for k_detail:
//      dk_s[b>>4][q][b&15]  (each wave-wid's stream is contiguous 64B rows).
__global__ __launch_bounds__(256) void k_dkred(
    const float* __restrict__ part, const float* __restrict__ bd,
    float* __restrict__ dk_s, int S)
{
  int t = threadIdx.x;
  int jj = blockIdx.x * 32 + (t >> 3);   // 680*32 = 21760 = B_*Q_ exactly
  int dl = t & 7;
  int b = jj / Q_, q = jj - b * Q_;
  int qt = q >> 6, ql = q & 63;
  const float* pp = part + (size_t)qt * 4096 + b * 64 + ql;
  float s = 0.f;
  for (int d = dl; d < S; d += 8) s += pp[(size_t)d * 6 * 4096];
  s += __shfl_xor(s, 1); s += __shfl_xor(s, 2); s += __shfl_xor(s, 4);
  if (dl == 0)
    dk_s[(size_t)(b >> 4) * (Q_ * 16) + q * 16 + (b & 15)] = bd[q] + s;
}

// ---- K4: detail einsum (R1-measured loop). dk rows via contiguous
//      s_load_dwordx16 stream per wave (dk_s layout); DPSD copy ping-pong.
__device__ __forceinline__ void dk_consume(const AS4 v16f* dkv, int qa,
                                           const float* dc, float* acc,
                                           float& sq, bool doSq)
{
  v16f r0 = dkv[qa + 0];
  v16f r1 = dkv[qa + 1];
  v16f r2 = dkv[qa + 2];
  v16f r3 = dkv[qa + 3];
  v16f r4 = dkv[qa + 4];
  if (doSq){
    #pragma unroll
    for (int i = 0; i < 5; i++) sq = fmaf(dc[i], dc[i], sq);
  }
  #pragma unroll
  for (int i = 0; i < 16; i++){
    acc[i] = fmaf(r0[i], dc[0], acc[i]);
    acc[i] = fmaf(r1[i], dc[1], acc[i]);
    acc[i] = fmaf(r2[i], dc[2], acc[i]);
    acc[i] = fmaf(r3[i], dc[3], acc[i]);
    acc[i] = fmaf(r4[i], dc[4], acc[i]);
  }
}

__global__ __launch_bounds__(256) void k_detail(
    const float* __restrict__ DPSD, const float* __restrict__ dk_s,
    float* __restrict__ stg, float* __restrict__ out,
    float* __restrict__ lacc, int qn)
{
  int t = threadIdx.x;
  int lane = t & 63;
  int wid = __builtin_amdgcn_readfirstlane(t >> 6);  // 0..3
  int b0 = wid * 16;
  int e = blockIdx.x * 64 + lane;
  bool ve = e < NE_;
  int q0 = blockIdx.y * qn;
  const AS4 v16f* dkv = univ16(dk_s + (size_t)wid * (Q_ * 16));
  const float* Dp = DPSD + (ve ? e : 0);
  float acc[16];
  #pragma unroll
  for (int i = 0; i < 16; i++) acc[i] = 0.f;
  float sq = 0.f;
  bool doSq = (wid == 0);
  int ng = qn / 5;                  // 68 / 34 : always even
  float da[5], db[5];
  #pragma unroll
  for (int i = 0; i < 5; i++) da[i] = Dp[(size_t)(q0 + i) * NE_];
  #pragma unroll
  for (int i = 0; i < 5; i++) db[i] = Dp[(size_t)(q0 + 5 + i) * NE_];
  for (int g = 0; g + 2 < ng; g += 2){
    int qa = q0 + g * 5;
    float ta[5], tb[5];
    #pragma unroll
    for (int i = 0; i < 5; i++) ta[i] = Dp[(size_t)(qa + 10 + i) * NE_];
    dk_consume(dkv, qa, da, acc, sq, doSq);
    #pragma unroll
    for (int i = 0; i < 5; i++) da[i] = ta[i];
    #pragma unroll
    for (int i = 0; i < 5; i++) tb[i] = Dp[(size_t)(qa + 15 + i) * NE_];
    dk_consume(dkv, qa + 5, db, acc, sq, doSq);
    #pragma unroll
    for (int i = 0; i < 5; i++) db[i] = tb[i];
  }
  dk_consume(dkv, q0 + (ng - 2) * 5, da, acc, sq, doSq);
  dk_consume(dkv, q0 + (ng - 1) * 5, db, acc, sq, doSq);
  if (ve){
    bool toOut = (blockIdx.y + 1 == gridDim.y);
    float* dst = toOut ? (out + 1 + e) : (stg + e);
    #pragma unroll
    for (int i = 0; i < 16; i++)
      dst[(size_t)(b0 + i) * NE_] = acc[i];
  }
  if (doSq){
    if (!ve) sq = 0.f;
    #pragma unroll
    for (int off = 32; off; off >>= 1) sq += __shfl_xor(sq, off);
    if (lane == 0) atomicAdd(&lacc[1], sq);
  }
}

// ---- K5: LBS skinning (R1-measured structure). G rows read as one
//      contiguous 96B run per j from the pre-swizzled G_sw.
__global__ __launch_bounds__(256) void k_skin(
    const float* __restrict__ G, const float* __restrict__ w_t,
    const float* __restrict__ rest, const float* __restrict__ in_pc,
    const float* __restrict__ stg, const float* __restrict__ rstd,
    const float* __restrict__ rmean,
    float* __restrict__ out, float* __restrict__ lacc, int two)
{
  int t = threadIdx.x;
  int lane = t & 63;
  int wid = __builtin_amdgcn_readfirstlane(t >> 6);  // 0..3
  int p  = blockIdx.x * 64 + lane;
  int bA = blockIdx.y * 8 + wid * 2;
  int bp = (blockIdx.y * 4 + wid);                  // pair index = bA>>1
  const AS4 v4f* gS = univ4(G + (size_t)bp * J_ * 24);
  float accA[12], accB[12];
  #pragma unroll
  for (int c = 0; c < 12; c++){ accA[c] = 0.f; accB[c] = 0.f; }
  const float* wp = w_t + p;
  #pragma unroll 4
  for (int j = 0; j < J_; j++){
    float w = wp[(size_t)j * PW_];
    v4f a0 = gS[j * 6 + 0], a1 = gS[j * 6 + 1], a2 = gS[j * 6 + 2];
    v4f c0 = gS[j * 6 + 3], c1 = gS[j * 6 + 4], c2 = gS[j * 6 + 5];
    #pragma unroll
    for (int c = 0; c < 4; c++){
      accA[c]     = fmaf(w, a0[c], accA[c]);
      accA[4 + c] = fmaf(w, a1[c], accA[4 + c]);
      accA[8 + c] = fmaf(w, a2[c], accA[8 + c]);
      accB[c]     = fmaf(w, c0[c], accB[c]);
      accB[4 + c] = fmaf(w, c1[c], accB[4 + c]);
      accB[8 + c] = fmaf(w, c2[c], accB[8 + c]);
    }
  }
  bool vp = p < P_;
  float vx = 0.f, vy = 0.f, vz = 0.f;
  if (vp){ vx = rest[p * 3]; vy = rest[p * 3 + 1]; vz = rest[p * 3 + 2]; }
  float srs[3], srm[3];
  #pragma unroll
  for (int x = 0; x < 3; x++){ srs[x] = rstd[x]; srm[x] = rmean[x]; }
  float lsum = 0.f;
  if (vp){
    size_t baseA = ((size_t)bA * P_ + p) * 3;
    size_t baseB = baseA + (size_t)P_ * 3;
    #pragma unroll
    for (int x = 0; x < 3; x++){
      float det = out[1 + baseA + x];
      if (two) det += stg[baseA + x];
      float v = fmaf(accA[x*4+0], vx, fmaf(accA[x*4+1], vy, fmaf(accA[x*4+2], vz, accA[x*4+3])));
      v += fmaf(det, srs[x], srm[x]);
      lsum += fabsf(in_pc[baseA + x] - v);
      out[1 + baseA + x] = v;
    }
    #pragma unroll
    for (int x = 0; x < 3; x++){
      float det = out[1 + baseB + x];
      if (two) det += stg[baseB + x];
      float v = fmaf(accB[x*4+0], vx, fmaf(accB[x*4+1], vy, fmaf(accB[x*4+2], vz, accB[x*4+3])));
      v += fmaf(det, srs[x], srm[x]);
      lsum += fabsf(in_pc[baseB + x] - v);
      out[1 + baseB + x] = v;
    }
  }
  #pragma unroll
  for (int off = 32; off; off >>= 1) lsum += __shfl_xor(lsum, off);
  __shared__ float red[4];
  if (lane == 0) red[wid] = lsum;
  __syncthreads();
  if (t == 0) atomicAdd(&lacc[0], red[0] + red[1] + red[2] + red[3]);
}

// ---- K6: finalize scalar loss
__global__ void k_finalize(const float* __restrict__ lacc, float* __restrict__ out){
  if (threadIdx.x == 0 && blockIdx.x == 0){
    float loss = lacc[0] * (1.f / 2356416.f) + 1e-4f * (lacc[1] * (1.f / 12518460.f));
    out[0] = loss;
  }
}

extern "C" void kernel_launch(void* const* d_in, const int* in_sizes, int n_in,
                              void* d_out, int out_size, void* d_ws, size_t ws_size,
                              hipStream_t stream){
  const float* in_pc = (const float*)d_in[0];
  const float* rest  = (const float*)d_in[2];
  const float* skin  = (const float*)d_in[3];
  const float* mwl   = (const float*)d_in[4];
  const float* query = (const float*)d_in[5];
  const float* cps   = (const float*)d_in[6];
  const float* cpm   = (const float*)d_in[7];
  const float* cts   = (const float*)d_in[8];
  const float* ctm   = (const float*)d_in[9];
  const float* W1    = (const float*)d_in[10];
  const float* b1    = (const float*)d_in[11];
  const float* W2    = (const float*)d_in[12];
  const float* b2    = (const float*)d_in[13];
  const float* tm    = (const float*)d_in[14];
  const float* Wd    = (const float*)d_in[15];
  const float* bd    = (const float*)d_in[16];
  const float* DPSD  = (const float*)d_in[17];
  const float* rstd  = (const float*)d_in[18];
  const float* rmean = (const float*)d_in[19];
  float* out = (float*)d_out;

  float* ws   = (float*)d_ws;
  float* G    = ws;                 // 61440 (swizzled pair layout)
  float* dk_s = G + 61440;          // 21760 (swizzled wid layout)
  float* lacc = dk_s + 21760;       // 64 (pad)
  float* tm_t = lacc + 64;          // 385024
  float* w_t  = tm_t + 385024;      // 983040
  float* un   = w_t + 983040;       // union: part (94*24576=2310144) then stg0 (2356416)
  // part is dead before k_detail writes stg0 -> alias them.

  size_t have = ws_size / 4;
  int nqh = (have >= (size_t)(1451328 + 2356416)) ? 2 : 1;
  int qn = Q_ / nqh;                // 340 / 170

  k_prep    <<<1567, 256, 0, stream>>>(query, mwl, tm, W1, b1, W2, b2,
                                       cps, cpm, cts, ctm, skin,
                                       G, tm_t, w_t, lacc);
  k_dkey    <<<dim3(6, 94), 256, 0, stream>>>(tm_t, Wd, un);
  k_dkred   <<<680, 256, 0, stream>>>(un, bd, dk_s, 94);
  k_detail  <<<dim3(576, nqh), 256, 0, stream>>>(DPSD, dk_s, un, out, lacc, qn);
  k_skin    <<<dim3(192, 8), 256, 0, stream>>>(G, w_t, rest, in_pc, un, rstd, rmean,
                                               out, lacc, nqh - 1);
  k_finalize<<<1, 64, 0, stream>>>(lacc, out);
}